// Round 3
// baseline (7301.428 us; speedup 1.0000x reference)
//
#include <hip/hip_runtime.h>
#include <cstdint>
#include <cstddef>

#define NB 64      // batch
#define LN 48      // buffer length
#define DN 256     // hidden dim
#define TKN 128    // tracker dim
#define TN 95      // steps = 2L-1
#define GA 512     // 4*TK
#define GR 1280    // 5*D
#define NWG 256
#define NT 512

__device__ __forceinline__ float sigf(float x) { return 1.0f / (1.0f + expf(-x)); }

__device__ __forceinline__ const float* row_ptr(int code, int b,
    const float* __restrict__ bufh, const float* __restrict__ redh) {
    if (code < 0) return nullptr;
    if (code >= 1000) return redh + ((size_t)(code - 1000) * NB + b) * DN;
    return bufh + ((size_t)b * LN + code) * DN;
}

// device-scope phase barrier: all NWG blocks co-resident (grid==NWG<=CUs)
__device__ __forceinline__ void gbar(unsigned* cnt, unsigned& ph) {
    __syncthreads();
    if (threadIdx.x == 0) {
        ph += 1;
        __hip_atomic_fetch_add(cnt, 1u, __ATOMIC_ACQ_REL, __HIP_MEMORY_SCOPE_AGENT);
        while (__hip_atomic_load(cnt, __ATOMIC_ACQUIRE, __HIP_MEMORY_SCOPE_AGENT) < ph * NWG) {
            __builtin_amdgcn_s_sleep(1);
        }
    }
    __syncthreads();
}

// ---------------- schedule builder (verified rounds 1-2) --------------------
__global__ void k_sched(const int* __restrict__ trans,
                        int* __restrict__ tbcode, int* __restrict__ s1code,
                        int* __restrict__ s2code, int* __restrict__ wkA,
                        int* __restrict__ fcode) {
    __shared__ int tg[NB][LN];
    int b = threadIdx.x;
    if (b >= NB) return;
    for (int i = 0; i < LN; ++i) tg[b][i] = -1;
    int sp = 0, bp = 0, k = 0;
    for (int t = 0; t < TN; ++t) {
        int tr = trans[b * TN + t];
        int shift = (tr == 0);
        int tb = (bp < LN) ? bp : -1;
        tbcode[t * NB + b] = tb;
        int i1 = sp - 1; if (i1 < 0) i1 = 0; if (i1 > LN - 1) i1 = LN - 1;
        int i2 = sp - 2; if (i2 < 0) i2 = 0; if (i2 > LN - 1) i2 = LN - 1;
        s1code[t * NB + b] = (sp >= 1) ? tg[b][i1] : -1;
        s2code[t * NB + b] = (sp >= 2) ? tg[b][i2] : -1;
        if (shift) {
            wkA[t * NB + b] = -1;
            if (sp >= 0 && sp < LN) tg[b][sp] = tb;
            sp = sp + 1;
            bp = bp + 1;
        } else {
            wkA[t * NB + b] = k;
            int pos = sp - 2; if (pos < 0) pos = 0;
            if (pos < LN) tg[b][pos] = 1000 + k;
            k++;
            sp = sp - 1; if (sp < 0) sp = 0;
        }
    }
    int fi = sp - 1; if (fi < 0) fi = 0; if (fi > LN - 1) fi = LN - 1;
    fcode[b] = tg[b][fi];
}

// ---------------- persistent full-scan kernel -------------------------------
__global__ __launch_bounds__(NT, 1) void k_spinn(
    const float* __restrict__ bufh, const float* __restrict__ bufc,
    const float* __restrict__ Wb, const float* __restrict__ W1,
    const float* __restrict__ W2, const float* __restrict__ Wl,
    const float* __restrict__ bl,
    const float* __restrict__ WLm, const float* __restrict__ bLv,
    const float* __restrict__ WRm, const float* __restrict__ WTm,
    const int* __restrict__ tbcode, const int* __restrict__ s1code,
    const int* __restrict__ s2code, const int* __restrict__ wkA,
    const int* __restrict__ fcode,
    float* __restrict__ th, float* __restrict__ tc,
    float* __restrict__ redh, float* __restrict__ redc,
    float* __restrict__ partial, unsigned* __restrict__ cnt,
    float* __restrict__ out) {
    const int wg = blockIdx.x;
    const int tid = threadIdx.x;
    const int lane = tid & 63;
    const int w = tid >> 6;                 // 8 waves
    unsigned ph = 0;

    __shared__ union {
        struct { float xs[896][2]; float part[8][64][2]; float gsum[2][64]; } g;
        struct { float xs2[160][4]; float part2[8][64][20]; } r;
    } sm;
    __shared__ int sc[8];

    const int bg = wg >> 3, jg = wg & 7;                          // P1: 32 bg x 8 jg
    const int rbg = wg & 15, rjg = (wg >> 4) & 3, rkg = wg >> 6;  // P2a: 16 x 4 x 4

    for (int t = 0; t < TN; ++t) {
        const int par = t & 1;
        // ================= P1: gates GEMM + tracker LSTM =================
        for (int bl_ = 0; bl_ < 2; ++bl_) {
            int b = bg * 2 + bl_;
            const float* tbp = row_ptr(tbcode[t * NB + b], b, bufh, redh);
            const float* s1p = row_ptr(s1code[t * NB + b], b, bufh, redh);
            const float* s2p = row_ptr(s2code[t * NB + b], b, bufh, redh);
            const float* thp = th + ((size_t)par * NB + b) * TKN;
            for (int k = tid; k < 896; k += NT) {
                float v;
                if (k < 256)      v = tbp ? tbp[k] : 0.f;
                else if (k < 512) v = s1p ? s1p[k - 256] : 0.f;
                else if (k < 768) v = s2p ? s2p[k - 512] : 0.f;
                else              v = thp[k - 768];
                sm.g.xs[k][bl_] = v;
            }
        }
        __syncthreads();
        {
            int q = lane >> 4, jj = lane & 15;
            int col = q * 128 + jg * 16 + jj;
            float a0 = 0.f, a1 = 0.f;
            int k0 = w * 112, k1 = k0 + 112;
            const float* const segb[4] = {Wb, W1, W2, Wl};
            const int segs[5] = {0, 256, 512, 768, 896};
            #pragma unroll
            for (int s = 0; s < 4; ++s) {
                int lo = k0 > segs[s] ? k0 : segs[s];
                int hi = k1 < segs[s + 1] ? k1 : segs[s + 1];
                const float* base = segb[s] + col;
                #pragma unroll 4
                for (int k = lo; k < hi; ++k) {
                    float wv = base[(size_t)(k - segs[s]) * GA];
                    float2 xv = *(const float2*)&sm.g.xs[k][0];
                    a0 += xv.x * wv;
                    a1 += xv.y * wv;
                }
            }
            sm.g.part[w][lane][0] = a0;
            sm.g.part[w][lane][1] = a1;
        }
        __syncthreads();
        if (w == 0) {
            float s0 = 0.f, s1 = 0.f;
            #pragma unroll
            for (int ww = 0; ww < 8; ++ww) { s0 += sm.g.part[ww][lane][0]; s1 += sm.g.part[ww][lane][1]; }
            int q = lane >> 4, jj = lane & 15;
            int col = q * 128 + jg * 16 + jj;
            if (t > 0) { float bv = bl[col]; s0 += bv; s1 += bv; }
            sm.g.gsum[0][lane] = s0;
            sm.g.gsum[1][lane] = s1;
        }
        __syncthreads();
        if (tid < 32) {
            int bl_ = tid >> 4, j2 = tid & 15;
            int b = bg * 2 + bl_;
            int j = jg * 16 + j2;
            float a = sm.g.gsum[bl_][j2];
            float i = sm.g.gsum[bl_][16 + j2];
            float f = sm.g.gsum[bl_][32 + j2];
            float o = sm.g.gsum[bl_][48 + j2];
            float tco = tc[((size_t)par * NB + b) * TKN + j];
            float c2 = tanhf(a) * sigf(i) + sigf(f) * tco;
            float h2 = sigf(o) * tanhf(c2);
            tc[((size_t)(par ^ 1) * NB + b) * TKN + j] = c2;
            th[((size_t)(par ^ 1) * NB + b) * TKN + j] = h2;
        }
        gbar(cnt, ph);   // barrier A: th2 visible

        // ================= P2a: rgates partial GEMM =================
        if (tid < 4) {
            int b = rbg * 4 + tid;
            sc[tid]     = s1code[t * NB + b];
            sc[4 + tid] = s2code[t * NB + b];
        }
        __syncthreads();
        {
            const int par2 = par ^ 1;
            for (int bl_ = 0; bl_ < 4; ++bl_) {
                int b = rbg * 4 + bl_;
                const float* s1p = row_ptr(sc[bl_], b, bufh, redh);
                const float* s2p = row_ptr(sc[4 + bl_], b, bufh, redh);
                const float* thp = th + ((size_t)par2 * NB + b) * TKN;
                for (int kk = tid; kk < 160; kk += NT) {
                    int kg = rkg * 160 + kk;
                    float v;
                    if (kg < 256)      v = s2p ? s2p[kg] : 0.f;
                    else if (kg < 512) v = s1p ? s1p[kg - 256] : 0.f;
                    else               v = thp[kg - 512];
                    sm.r.xs2[kk][bl_] = v;
                }
            }
        }
        __syncthreads();
        {
            int jglob = rjg * 64 + lane;
            float acc[4][5];
            #pragma unroll
            for (int b4 = 0; b4 < 4; ++b4)
                #pragma unroll
                for (int g = 0; g < 5; ++g) acc[b4][g] = 0.f;
            for (int kr = 0; kr < 20; ++kr) {
                int kk = w * 20 + kr;
                int kg = rkg * 160 + kk;
                const float* wrow;
                if (kg < 256)      wrow = WLm + (size_t)kg * GR;
                else if (kg < 512) wrow = WRm + (size_t)(kg - 256) * GR;
                else               wrow = WTm + (size_t)(kg - 512) * GR;
                float4 xv = *(const float4*)&sm.r.xs2[kk][0];
                #pragma unroll
                for (int g = 0; g < 5; ++g) {
                    float wv = wrow[g * 256 + jglob];
                    acc[0][g] += xv.x * wv;
                    acc[1][g] += xv.y * wv;
                    acc[2][g] += xv.z * wv;
                    acc[3][g] += xv.w * wv;
                }
            }
            #pragma unroll
            for (int b4 = 0; b4 < 4; ++b4)
                #pragma unroll
                for (int g = 0; g < 5; ++g) sm.r.part2[w][lane][b4 * 5 + g] = acc[b4][g];
        }
        __syncthreads();
        for (int idx = tid; idx < 1280; idx += NT) {
            int bl_ = idx / 320, rem = idx % 320;
            int jl = rem / 5, g = rem % 5;
            float s = 0.f;
            #pragma unroll
            for (int ww = 0; ww < 8; ++ww) s += sm.r.part2[ww][jl][bl_ * 5 + g];
            int b = rbg * 4 + bl_;
            int jglob = rjg * 64 + jl;
            partial[(((size_t)b * 256 + jglob) * 5 + g) * 4 + rkg] = s;
        }
        gbar(cnt, ph);   // barrier B: partials visible

        // ================= P2b: kg-sum + TreeLSTM =================
        if (tid < 64) {
            int o = wg * 64 + tid;
            int b = o >> 8, j = o & 255;
            int wk = wkA[t * NB + b];
            if (wk >= 0) {
                float g[5];
                const float* pb = partial + ((size_t)b * 256 + j) * 20;
                #pragma unroll
                for (int gi = 0; gi < 5; ++gi) {
                    float4 p4 = *(const float4*)(pb + gi * 4);
                    g[gi] = p4.x + p4.y + p4.z + p4.w + bLv[gi * 256 + j];
                }
                int c1 = s1code[t * NB + b], c2 = s2code[t * NB + b];
                float s2cv = (c2 == -1) ? 0.f
                            : ((c2 >= 1000) ? redc[((size_t)(c2 - 1000) * NB + b) * DN + j]
                                            : bufc[((size_t)b * LN + c2) * DN + j]);
                float s1cv = (c1 == -1) ? 0.f
                            : ((c1 >= 1000) ? redc[((size_t)(c1 - 1000) * NB + b) * DN + j]
                                            : bufc[((size_t)b * LN + c1) * DN + j]);
                float cc = tanhf(g[0]) * sigf(g[1]) + sigf(g[2]) * s2cv + sigf(g[3]) * s1cv;
                float hh = sigf(g[4]) * tanhf(cc);
                redh[((size_t)wk * NB + b) * DN + j] = hh;
                redc[((size_t)wk * NB + b) * DN + j] = cc;
            }
        }
        gbar(cnt, ph);   // barrier C: redh/redc visible
    }

    // ================= final gather =================
    if (tid < 128) {
        int idx = wg * 128 + tid;
        int b = idx / (2 * DN);
        int e = idx % (2 * DN);
        int c = fcode[b];
        float v = 0.f;
        if (c != -1) {
            if (e < DN)
                v = (c >= 1000) ? redh[((size_t)(c - 1000) * NB + b) * DN + e]
                                : bufh[((size_t)b * LN + c) * DN + e];
            else {
                int e2 = e - DN;
                v = (c >= 1000) ? redc[((size_t)(c - 1000) * NB + b) * DN + e2]
                                : bufc[((size_t)b * LN + c) * DN + e2];
            }
        }
        out[idx] = v;
    }
}

extern "C" void kernel_launch(void* const* d_in, const int* in_sizes, int n_in,
                              void* d_out, int out_size, void* d_ws, size_t ws_size,
                              hipStream_t stream) {
    const float* bufh = (const float*)d_in[0];
    const float* bufc = (const float*)d_in[1];
    const float* Wb   = (const float*)d_in[2];
    const float* W1   = (const float*)d_in[3];
    const float* W2   = (const float*)d_in[4];
    const float* Wl   = (const float*)d_in[5];
    const float* bl   = (const float*)d_in[6];
    const float* WLm  = (const float*)d_in[7];
    const float* bLv  = (const float*)d_in[8];
    const float* WR   = (const float*)d_in[9];
    const float* WT   = (const float*)d_in[10];
    const int* trans  = (const int*)d_in[11];
    float* out = (float*)d_out;

    char* p = (char*)d_ws;
    auto carve = [&](size_t bytes) -> char* {
        char* r = p;
        p += (bytes + 255) & ~(size_t)255;
        return r;
    };
    int* tbcode = (int*)carve((size_t)TN * NB * 4);
    int* s1code = (int*)carve((size_t)TN * NB * 4);
    int* s2code = (int*)carve((size_t)TN * NB * 4);
    int* wkA    = (int*)carve((size_t)TN * NB * 4);
    int* fcode  = (int*)carve((size_t)NB * 4);
    float* th   = (float*)carve((size_t)2 * NB * TKN * 4);
    float* tc   = (float*)carve((size_t)2 * NB * TKN * 4);
    float* redh = (float*)carve((size_t)TN * NB * DN * 4);
    float* redc = (float*)carve((size_t)TN * NB * DN * 4);
    float* partial = (float*)carve((size_t)NB * 256 * 5 * 4 * 4);
    unsigned* cnt  = (unsigned*)carve(256);

    hipMemsetAsync(th, 0, (size_t)2 * NB * TKN * 4, stream);
    hipMemsetAsync(tc, 0, (size_t)2 * NB * TKN * 4, stream);
    hipMemsetAsync(cnt, 0, 256, stream);

    k_sched<<<1, 64, 0, stream>>>(trans, tbcode, s1code, s2code, wkA, fcode);
    k_spinn<<<NWG, NT, 0, stream>>>(bufh, bufc, Wb, W1, W2, Wl, bl,
                                    WLm, bLv, WR, WT,
                                    tbcode, s1code, s2code, wkA, fcode,
                                    th, tc, redh, redc, partial, cnt, out);
}

// Round 4
// 3584.119 us; speedup vs baseline: 2.0372x; 2.0372x over previous
//
#include <hip/hip_runtime.h>
#include <cstdint>
#include <cstddef>

#define NB 64      // batch
#define LN 48      // buffer length
#define DN 256     // hidden dim
#define TKN 128    // tracker dim
#define TN 95      // steps = 2L-1
#define GA 512     // 4*TK
#define GR 1280    // 5*D
#define NWG 256
#define NT 512

__device__ __forceinline__ float sigf(float x) { return 1.0f / (1.0f + expf(-x)); }

// coherent (sc1) scalar access — bypasses non-coherent per-XCD L2, no wbl2/inv
__device__ __forceinline__ float cohLd(const float* p) {
    return __hip_atomic_load(p, __ATOMIC_RELAXED, __HIP_MEMORY_SCOPE_AGENT);
}
__device__ __forceinline__ void cohSt(float* p, float v) {
    __hip_atomic_store(p, v, __ATOMIC_RELAXED, __HIP_MEMORY_SCOPE_AGENT);
}

// grid barrier: __syncthreads drains vmcnt(0) (compiler-emitted before s_barrier),
// so all waves' sc1 stores are at the coherence point before the relaxed arrival.
__device__ __forceinline__ void gbar(unsigned* cnt, unsigned& ph) {
    __syncthreads();
    if (threadIdx.x == 0) {
        ph += 1;
        __hip_atomic_fetch_add(cnt, 1u, __ATOMIC_RELAXED, __HIP_MEMORY_SCOPE_AGENT);
        while (__hip_atomic_load(cnt, __ATOMIC_RELAXED, __HIP_MEMORY_SCOPE_AGENT) < ph * NWG) {
            __builtin_amdgcn_s_sleep(2);
        }
        asm volatile("" ::: "memory");
    }
    __syncthreads();
}

// ---------------- schedule builder: 1 wg, 64 threads (one per batch) --------
// tag codes: -1 = zeros, 0..47 = BUF idx, 1000+k = RED k
__global__ void k_sched(const int* __restrict__ trans,
                        int* __restrict__ tbcode, int* __restrict__ s1code,
                        int* __restrict__ s2code, int* __restrict__ wkA,
                        int* __restrict__ fcode, int* __restrict__ anyred) {
    __shared__ int tg[NB][LN];
    int b = threadIdx.x;
    if (b >= NB) return;
    for (int i = 0; i < LN; ++i) tg[b][i] = -1;
    int sp = 0, bp = 0, k = 0;
    for (int t = 0; t < TN; ++t) {
        int tr = trans[b * TN + t];
        int shift = (tr == 0);
        int tb = (bp < LN) ? bp : -1;
        tbcode[t * NB + b] = tb;
        int i1 = sp - 1; if (i1 < 0) i1 = 0; if (i1 > LN - 1) i1 = LN - 1;
        int i2 = sp - 2; if (i2 < 0) i2 = 0; if (i2 > LN - 1) i2 = LN - 1;
        s1code[t * NB + b] = (sp >= 1) ? tg[b][i1] : -1;
        s2code[t * NB + b] = (sp >= 2) ? tg[b][i2] : -1;
        int wk_t;
        if (shift) {
            wk_t = -1;
            if (sp >= 0 && sp < LN) tg[b][sp] = tb;
            sp = sp + 1;
            bp = bp + 1;
        } else {
            wk_t = k;
            int pos = sp - 2; if (pos < 0) pos = 0;
            if (pos < LN) tg[b][pos] = 1000 + k;
            k++;
            sp = sp - 1; if (sp < 0) sp = 0;
        }
        wkA[t * NB + b] = wk_t;
        unsigned long long m = __ballot(wk_t >= 0);
        if (b == 0) anyred[t] = (m != 0ull) ? 1 : 0;
    }
    int fi = sp - 1; if (fi < 0) fi = 0; if (fi > LN - 1) fi = LN - 1;
    fcode[b] = tg[b][fi];
}

// ---------------- persistent full-scan kernel -------------------------------
__global__ __launch_bounds__(NT, 1) void k_spinn(
    const float* __restrict__ bufh, const float* __restrict__ bufc,
    const float* __restrict__ Wb, const float* __restrict__ W1,
    const float* __restrict__ W2, const float* __restrict__ Wl,
    const float* __restrict__ bl,
    const float* __restrict__ WLm, const float* __restrict__ bLv,
    const float* __restrict__ WRm, const float* __restrict__ WTm,
    const int* __restrict__ tbcode, const int* __restrict__ s1code,
    const int* __restrict__ s2code, const int* __restrict__ wkA,
    const int* __restrict__ fcode, const int* __restrict__ anyred,
    float* __restrict__ th, float* __restrict__ tc,
    float* __restrict__ redh, float* __restrict__ redc,
    float* __restrict__ partial, unsigned* __restrict__ cnt,
    float* __restrict__ out) {
    const int wg = blockIdx.x;
    const int tid = threadIdx.x;
    const int lane = tid & 63;
    const int w = tid >> 6;                 // 8 waves
    unsigned ph = 0;

    __shared__ union {
        struct { float xs[896][2]; float part[8][64][2]; float gsum[2][64]; } g;
        struct { float xs2[160][4]; float part2[8][64][21]; } r;   // padded 21
    } sm;
    __shared__ int sc[8];

    const int bg = wg >> 3, jg = wg & 7;                          // P1: 32 bg x 8 jg
    const int rbg = wg & 15, rjg = (wg >> 4) & 3, rkg = wg >> 6;  // P2a: 16 x 4 x 4

    for (int t = 0; t < TN; ++t) {
        const int par = t & 1;
        // ================= P1: gates GEMM + tracker LSTM =================
        for (int bl_ = 0; bl_ < 2; ++bl_) {
            int b = bg * 2 + bl_;
            int ctb = tbcode[t * NB + b];
            int c1  = s1code[t * NB + b];
            int c2  = s2code[t * NB + b];
            for (int k = tid; k < 896; k += NT) {
                float v = 0.f;
                if (k < 256) {
                    if (ctb >= 0) v = bufh[((size_t)b * LN + ctb) * DN + k];
                } else if (k < 512) {
                    int kk = k - 256;
                    if (c1 >= 1000)     v = cohLd(&redh[((size_t)(c1 - 1000) * NB + b) * DN + kk]);
                    else if (c1 >= 0)   v = bufh[((size_t)b * LN + c1) * DN + kk];
                } else if (k < 768) {
                    int kk = k - 512;
                    if (c2 >= 1000)     v = cohLd(&redh[((size_t)(c2 - 1000) * NB + b) * DN + kk]);
                    else if (c2 >= 0)   v = bufh[((size_t)b * LN + c2) * DN + kk];
                } else {
                    v = cohLd(&th[((size_t)par * NB + b) * TKN + (k - 768)]);
                }
                sm.g.xs[k][bl_] = v;
            }
        }
        __syncthreads();
        {
            int q = lane >> 4, jj = lane & 15;
            int col = q * 128 + jg * 16 + jj;
            float a0 = 0.f, a1 = 0.f;
            int k0 = w * 112, k1 = k0 + 112;
            const float* const segb[4] = {Wb, W1, W2, Wl};
            const int segs[5] = {0, 256, 512, 768, 896};
            #pragma unroll
            for (int s = 0; s < 4; ++s) {
                int lo = k0 > segs[s] ? k0 : segs[s];
                int hi = k1 < segs[s + 1] ? k1 : segs[s + 1];
                const float* base = segb[s] + col;
                #pragma unroll 4
                for (int k = lo; k < hi; ++k) {
                    float wv = base[(size_t)(k - segs[s]) * GA];
                    float2 xv = *(const float2*)&sm.g.xs[k][0];
                    a0 += xv.x * wv;
                    a1 += xv.y * wv;
                }
            }
            sm.g.part[w][lane][0] = a0;
            sm.g.part[w][lane][1] = a1;
        }
        __syncthreads();
        if (w == 0) {
            float s0 = 0.f, s1 = 0.f;
            #pragma unroll
            for (int ww = 0; ww < 8; ++ww) { s0 += sm.g.part[ww][lane][0]; s1 += sm.g.part[ww][lane][1]; }
            int q = lane >> 4, jj = lane & 15;
            int col = q * 128 + jg * 16 + jj;
            if (t > 0) { float bv = bl[col]; s0 += bv; s1 += bv; }
            sm.g.gsum[0][lane] = s0;
            sm.g.gsum[1][lane] = s1;
        }
        __syncthreads();
        if (tid < 32) {
            int bl_ = tid >> 4, j2 = tid & 15;
            int b = bg * 2 + bl_;
            int j = jg * 16 + j2;
            float a = sm.g.gsum[bl_][j2];
            float i = sm.g.gsum[bl_][16 + j2];
            float f = sm.g.gsum[bl_][32 + j2];
            float o = sm.g.gsum[bl_][48 + j2];
            float tco = tc[((size_t)par * NB + b) * TKN + j];      // WG-local, plain
            float c2v = tanhf(a) * sigf(i) + sigf(f) * tco;
            float h2 = sigf(o) * tanhf(c2v);
            tc[((size_t)(par ^ 1) * NB + b) * TKN + j] = c2v;      // WG-local, plain
            cohSt(&th[((size_t)(par ^ 1) * NB + b) * TKN + j], h2); // cross-WG
        }
        gbar(cnt, ph);   // barrier A: th2 visible

        if (anyred[t]) {
            // ================= P2a: rgates partial GEMM =================
            if (tid < 4) {
                int b = rbg * 4 + tid;
                sc[tid]     = s1code[t * NB + b];
                sc[4 + tid] = s2code[t * NB + b];
            }
            __syncthreads();
            {
                const int par2 = par ^ 1;
                for (int bl_ = 0; bl_ < 4; ++bl_) {
                    int b = rbg * 4 + bl_;
                    int c1 = sc[bl_], c2 = sc[4 + bl_];
                    for (int kk = tid; kk < 160; kk += NT) {
                        int kg = rkg * 160 + kk;
                        float v = 0.f;
                        if (kg < 256) {
                            if (c2 >= 1000)   v = cohLd(&redh[((size_t)(c2 - 1000) * NB + b) * DN + kg]);
                            else if (c2 >= 0) v = bufh[((size_t)b * LN + c2) * DN + kg];
                        } else if (kg < 512) {
                            int k2 = kg - 256;
                            if (c1 >= 1000)   v = cohLd(&redh[((size_t)(c1 - 1000) * NB + b) * DN + k2]);
                            else if (c1 >= 0) v = bufh[((size_t)b * LN + c1) * DN + k2];
                        } else {
                            v = cohLd(&th[((size_t)par2 * NB + b) * TKN + (kg - 512)]);
                        }
                        sm.r.xs2[kk][bl_] = v;
                    }
                }
            }
            __syncthreads();
            {
                int jglob = rjg * 64 + lane;
                float acc[4][5];
                #pragma unroll
                for (int b4 = 0; b4 < 4; ++b4)
                    #pragma unroll
                    for (int g = 0; g < 5; ++g) acc[b4][g] = 0.f;
                for (int kr = 0; kr < 20; ++kr) {
                    int kk = w * 20 + kr;
                    int kg = rkg * 160 + kk;
                    const float* wrow;
                    if (kg < 256)      wrow = WLm + (size_t)kg * GR;
                    else if (kg < 512) wrow = WRm + (size_t)(kg - 256) * GR;
                    else               wrow = WTm + (size_t)(kg - 512) * GR;
                    float4 xv = *(const float4*)&sm.r.xs2[kk][0];
                    #pragma unroll
                    for (int g = 0; g < 5; ++g) {
                        float wv = wrow[g * 256 + jglob];
                        acc[0][g] += xv.x * wv;
                        acc[1][g] += xv.y * wv;
                        acc[2][g] += xv.z * wv;
                        acc[3][g] += xv.w * wv;
                    }
                }
                #pragma unroll
                for (int b4 = 0; b4 < 4; ++b4)
                    #pragma unroll
                    for (int g = 0; g < 5; ++g) sm.r.part2[w][lane][b4 * 5 + g] = acc[b4][g];
            }
            __syncthreads();
            for (int idx = tid; idx < 1280; idx += NT) {
                int bl_ = idx / 320, rem = idx % 320;
                int jl = rem / 5, g = rem % 5;
                float s = 0.f;
                #pragma unroll
                for (int ww = 0; ww < 8; ++ww) s += sm.r.part2[ww][jl][bl_ * 5 + g];
                int b = rbg * 4 + bl_;
                int jglob = rjg * 64 + jl;
                cohSt(&partial[(((size_t)b * 256 + jglob) * 5 + g) * 4 + rkg], s);
            }
            gbar(cnt, ph);   // barrier B: partials visible

            // ================= P2b: kg-sum + TreeLSTM =================
            if (tid < 64) {
                int o = wg * 64 + tid;
                int b = o >> 8, j = o & 255;
                int wk = wkA[t * NB + b];
                if (wk >= 0) {
                    float g[5];
                    const float* pb = partial + ((size_t)b * 256 + j) * 20;
                    #pragma unroll
                    for (int gi = 0; gi < 5; ++gi) {
                        float s = 0.f;
                        #pragma unroll
                        for (int r = 0; r < 4; ++r) s += cohLd(pb + gi * 4 + r);
                        g[gi] = s + bLv[gi * 256 + j];
                    }
                    int c1 = s1code[t * NB + b], c2 = s2code[t * NB + b];
                    float s2cv = (c2 == -1) ? 0.f
                                : ((c2 >= 1000) ? redc[((size_t)(c2 - 1000) * NB + b) * DN + j]   // owner-local
                                                : bufc[((size_t)b * LN + c2) * DN + j]);
                    float s1cv = (c1 == -1) ? 0.f
                                : ((c1 >= 1000) ? redc[((size_t)(c1 - 1000) * NB + b) * DN + j]
                                                : bufc[((size_t)b * LN + c1) * DN + j]);
                    float cc = tanhf(g[0]) * sigf(g[1]) + sigf(g[2]) * s2cv + sigf(g[3]) * s1cv;
                    float hh = sigf(g[4]) * tanhf(cc);
                    cohSt(&redh[((size_t)wk * NB + b) * DN + j], hh);   // cross-WG
                    redc[((size_t)wk * NB + b) * DN + j] = cc;          // owner-local
                }
            }
            gbar(cnt, ph);   // barrier C: redh visible
        }
    }

    // ================= final output: owner (b,j) writes, no barrier needed ====
    if (tid < 64) {
        int o = wg * 64 + tid;
        int b = o >> 8, j = o & 255;
        int c = fcode[b];
        float h = 0.f, cv = 0.f;
        if (c >= 1000) {
            h  = cohLd(&redh[((size_t)(c - 1000) * NB + b) * DN + j]);
            cv = redc[((size_t)(c - 1000) * NB + b) * DN + j];
        } else if (c >= 0) {
            h  = bufh[((size_t)b * LN + c) * DN + j];
            cv = bufc[((size_t)b * LN + c) * DN + j];
        }
        out[(size_t)b * 2 * DN + j]      = h;
        out[(size_t)b * 2 * DN + DN + j] = cv;
    }
}

extern "C" void kernel_launch(void* const* d_in, const int* in_sizes, int n_in,
                              void* d_out, int out_size, void* d_ws, size_t ws_size,
                              hipStream_t stream) {
    const float* bufh = (const float*)d_in[0];
    const float* bufc = (const float*)d_in[1];
    const float* Wb   = (const float*)d_in[2];
    const float* W1   = (const float*)d_in[3];
    const float* W2   = (const float*)d_in[4];
    const float* Wl   = (const float*)d_in[5];
    const float* bl   = (const float*)d_in[6];
    const float* WLm  = (const float*)d_in[7];
    const float* bLv  = (const float*)d_in[8];
    const float* WR   = (const float*)d_in[9];
    const float* WT   = (const float*)d_in[10];
    const int* trans  = (const int*)d_in[11];
    float* out = (float*)d_out;

    char* p = (char*)d_ws;
    auto carve = [&](size_t bytes) -> char* {
        char* r = p;
        p += (bytes + 255) & ~(size_t)255;
        return r;
    };
    int* tbcode = (int*)carve((size_t)TN * NB * 4);
    int* s1code = (int*)carve((size_t)TN * NB * 4);
    int* s2code = (int*)carve((size_t)TN * NB * 4);
    int* wkA    = (int*)carve((size_t)TN * NB * 4);
    int* fcode  = (int*)carve((size_t)NB * 4);
    int* anyred = (int*)carve((size_t)TN * 4);
    float* th   = (float*)carve((size_t)2 * NB * TKN * 4);
    float* tc   = (float*)carve((size_t)2 * NB * TKN * 4);
    float* redh = (float*)carve((size_t)TN * NB * DN * 4);
    float* redc = (float*)carve((size_t)TN * NB * DN * 4);
    float* partial = (float*)carve((size_t)NB * 256 * 5 * 4 * 4);
    unsigned* cnt  = (unsigned*)carve(256);

    hipMemsetAsync(th, 0, (size_t)2 * NB * TKN * 4, stream);
    hipMemsetAsync(tc, 0, (size_t)2 * NB * TKN * 4, stream);
    hipMemsetAsync(cnt, 0, 256, stream);

    k_sched<<<1, 64, 0, stream>>>(trans, tbcode, s1code, s2code, wkA, fcode, anyred);
    k_spinn<<<NWG, NT, 0, stream>>>(bufh, bufc, Wb, W1, W2, Wl, bl,
                                    WLm, bLv, WR, WT,
                                    tbcode, s1code, s2code, wkA, fcode, anyred,
                                    th, tc, redh, redc, partial, cnt, out);
}

// Round 5
// 2092.480 us; speedup vs baseline: 3.4894x; 1.7129x over previous
//
#include <hip/hip_runtime.h>
#include <cstdint>
#include <cstddef>

#define NB 64      // batch
#define LN 48      // buffer length
#define DN 256     // hidden dim
#define TKN 128    // tracker dim
#define TN 95      // steps = 2L-1
#define GA 512     // 4*TK
#define GR 1280    // 5*D
#define NWG 256
#define NT 512

__device__ __forceinline__ float sigf(float x) { return 1.0f / (1.0f + expf(-x)); }

// coherent (sc1) scalar access — bypasses non-coherent per-XCD L2
__device__ __forceinline__ float cohLd(const float* p) {
    return __hip_atomic_load(p, __ATOMIC_RELAXED, __HIP_MEMORY_SCOPE_AGENT);
}
__device__ __forceinline__ void cohSt(float* p, float v) {
    __hip_atomic_store(p, v, __ATOMIC_RELAXED, __HIP_MEMORY_SCOPE_AGENT);
}

// decoupled grid barrier: arrival RMW on cnt, spin read-only on flag (separate line).
// __syncthreads() drains vmcnt(0) before s_barrier, so all sc1 stores are at the
// coherence point before thread 0 arrives (visibility scheme verified rounds 4).
__device__ __forceinline__ void gbar(unsigned* cnt, unsigned* flag, unsigned& ph) {
    __syncthreads();
    if (threadIdx.x == 0) {
        ph += 1;
        unsigned old = __hip_atomic_fetch_add(cnt, 1u, __ATOMIC_RELAXED, __HIP_MEMORY_SCOPE_AGENT);
        if (old == ph * NWG - 1u) {
            __hip_atomic_store(flag, ph, __ATOMIC_RELAXED, __HIP_MEMORY_SCOPE_AGENT);
        } else {
            while (__hip_atomic_load(flag, __ATOMIC_RELAXED, __HIP_MEMORY_SCOPE_AGENT) < ph)
                __builtin_amdgcn_s_sleep(2);
        }
        asm volatile("" ::: "memory");
    }
    __syncthreads();
}

// ---------------- schedule builder: 1 wg, 64 threads (one per batch) --------
// tag codes: -1 = zeros, 0..47 = BUF idx, 1000+k = RED k
__global__ void k_sched(const int* __restrict__ trans,
                        int* __restrict__ tbcode, int* __restrict__ s1code,
                        int* __restrict__ s2code, int* __restrict__ wkA,
                        int* __restrict__ fcode, int* __restrict__ anyred) {
    __shared__ int tg[NB][LN];
    int b = threadIdx.x;
    if (b >= NB) return;
    for (int i = 0; i < LN; ++i) tg[b][i] = -1;
    int sp = 0, bp = 0, k = 0;
    for (int t = 0; t < TN; ++t) {
        int tr = trans[b * TN + t];
        int shift = (tr == 0);
        int tb = (bp < LN) ? bp : -1;
        tbcode[t * NB + b] = tb;
        int i1 = sp - 1; if (i1 < 0) i1 = 0; if (i1 > LN - 1) i1 = LN - 1;
        int i2 = sp - 2; if (i2 < 0) i2 = 0; if (i2 > LN - 1) i2 = LN - 1;
        s1code[t * NB + b] = (sp >= 1) ? tg[b][i1] : -1;
        s2code[t * NB + b] = (sp >= 2) ? tg[b][i2] : -1;
        int wk_t;
        if (shift) {
            wk_t = -1;
            if (sp >= 0 && sp < LN) tg[b][sp] = tb;
            sp = sp + 1;
            bp = bp + 1;
        } else {
            wk_t = k;
            int pos = sp - 2; if (pos < 0) pos = 0;
            if (pos < LN) tg[b][pos] = 1000 + k;
            k++;
            sp = sp - 1; if (sp < 0) sp = 0;
        }
        wkA[t * NB + b] = wk_t;
        unsigned long long m = __ballot(wk_t >= 0);
        if (b == 0) anyred[t] = (m != 0ull) ? 1 : 0;
    }
    int fi = sp - 1; if (fi < 0) fi = 0; if (fi > LN - 1) fi = LN - 1;
    fcode[b] = tg[b][fi];
}

// ---------------- persistent full-scan kernel -------------------------------
__global__ __launch_bounds__(NT, 1) void k_spinn(
    const float* __restrict__ bufh, const float* __restrict__ bufc,
    const float* __restrict__ Wb, const float* __restrict__ W1,
    const float* __restrict__ W2, const float* __restrict__ Wl,
    const float* __restrict__ blv,
    const float* __restrict__ WLm, const float* __restrict__ bLv,
    const float* __restrict__ WRm, const float* __restrict__ WTm,
    const int* __restrict__ tbcode, const int* __restrict__ s1code,
    const int* __restrict__ s2code, const int* __restrict__ wkA,
    const int* __restrict__ fcode, const int* __restrict__ anyred,
    float* __restrict__ th, float* __restrict__ tc,
    float* __restrict__ redh, float* __restrict__ redc,
    unsigned* __restrict__ cnt, unsigned* __restrict__ flag,
    float* __restrict__ out) {
    const int wg = blockIdx.x;
    const int tid = threadIdx.x;
    const int lane = tid & 63;
    const int w = tid >> 6;                 // 8 waves
    unsigned ph = 0;

    // XCD-pinned decompositions (xcd = wg & 7 — perf heuristic only)
    const int xcd = wg & 7;
    const int u = wg >> 3;                  // 0..31
    // P1: 8 bg (8 b) x 32 jg (4 tracker-j x 4 quadrants = 16 cols); jg pinned to xcd
    const int bg1 = u & 7;
    const int jg1 = xcd * 4 + (u >> 3);     // 0..31
    // P2: 16 bg (4 b) x 16 jgw (16 j x 5 gates = 80 cols); jgw pinned to xcd
    const int bg2 = u >> 1;                 // 0..15
    const int jgw = (u & 1) + 2 * xcd;      // 0..15

    __shared__ union {
        struct { float xs[8][896]; float part1[8][64][2]; float gsum[8][16]; } p1;
        struct { float xs2[4][640]; float part2[4][5][33][16]; float gsum2[4][5][16]; } p2;
    } sm;

    for (int t = 0; t < TN; ++t) {
        const int par = t & 1;
        // ================= P1: gates GEMM + tracker LSTM =================
        for (int bl_ = 0; bl_ < 8; ++bl_) {
            int b = bg1 * 8 + bl_;
            int ctb = tbcode[t * NB + b];
            int c1  = s1code[t * NB + b];
            int c2  = s2code[t * NB + b];
            for (int k = tid; k < 896; k += NT) {
                float v = 0.f;
                if (k < 256) {
                    if (ctb >= 0) v = bufh[((size_t)b * LN + ctb) * DN + k];
                } else if (k < 512) {
                    int kk = k - 256;
                    if (c1 >= 1000)     v = cohLd(&redh[((size_t)(c1 - 1000) * NB + b) * DN + kk]);
                    else if (c1 >= 0)   v = bufh[((size_t)b * LN + c1) * DN + kk];
                } else if (k < 768) {
                    int kk = k - 512;
                    if (c2 >= 1000)     v = cohLd(&redh[((size_t)(c2 - 1000) * NB + b) * DN + kk]);
                    else if (c2 >= 0)   v = bufh[((size_t)b * LN + c2) * DN + kk];
                } else {
                    v = cohLd(&th[((size_t)par * NB + b) * TKN + (k - 768)]);
                }
                sm.p1.xs[bl_][k] = v;
            }
        }
        __syncthreads();
        {
            int colL = lane & 15, bh = lane >> 4;     // col 16, b-half 4 (2 b each)
            int q = colL >> 2, jo = colL & 3;
            int col = q * 128 + jg1 * 4 + jo;
            int bl0 = bh * 2, bl1 = bh * 2 + 1;
            float a0 = 0.f, a1 = 0.f;
            int k0 = w * 112, k1 = k0 + 112;
            const float* const segb[4] = {Wb, W1, W2, Wl};
            const int segs[5] = {0, 256, 512, 768, 896};
            #pragma unroll
            for (int s = 0; s < 4; ++s) {
                int lo = k0 > segs[s] ? k0 : segs[s];
                int hi = k1 < segs[s + 1] ? k1 : segs[s + 1];
                const float* base = segb[s] + col;
                #pragma unroll 4
                for (int k = lo; k < hi; ++k) {
                    float wv = base[(size_t)(k - segs[s]) * GA];
                    a0 += sm.p1.xs[bl0][k] * wv;
                    a1 += sm.p1.xs[bl1][k] * wv;
                }
            }
            sm.p1.part1[w][lane][0] = a0;
            sm.p1.part1[w][lane][1] = a1;
        }
        __syncthreads();
        if (w == 0) {
            float s0 = 0.f, s1 = 0.f;
            #pragma unroll
            for (int ww = 0; ww < 8; ++ww) { s0 += sm.p1.part1[ww][lane][0]; s1 += sm.p1.part1[ww][lane][1]; }
            int colL = lane & 15, bh = lane >> 4;
            int q = colL >> 2, jo = colL & 3;
            int col = q * 128 + jg1 * 4 + jo;
            if (t > 0) { float bv = blv[col]; s0 += bv; s1 += bv; }
            sm.p1.gsum[bh * 2][colL]     = s0;
            sm.p1.gsum[bh * 2 + 1][colL] = s1;
        }
        __syncthreads();
        if (tid < 32) {
            int bloc = tid >> 2, jj4 = tid & 3;
            int b = bg1 * 8 + bloc;
            int j = jg1 * 4 + jj4;
            float a = sm.p1.gsum[bloc][jj4];
            float i = sm.p1.gsum[bloc][4 + jj4];
            float f = sm.p1.gsum[bloc][8 + jj4];
            float o = sm.p1.gsum[bloc][12 + jj4];
            float tco = tc[((size_t)par * NB + b) * TKN + j];       // owner-stable, plain
            float c2v = tanhf(a) * sigf(i) + sigf(f) * tco;
            float h2 = sigf(o) * tanhf(c2v);
            tc[((size_t)(par ^ 1) * NB + b) * TKN + j] = c2v;       // owner-stable, plain
            cohSt(&th[((size_t)(par ^ 1) * NB + b) * TKN + j], h2); // cross-WG
        }
        gbar(cnt, flag, ph);   // barrier A: th2 visible

        if (anyred[t]) {
            // ===== P2: full-K rgates GEMM + in-WG TreeLSTM (no partial exchange) =====
            const int par2 = par ^ 1;
            for (int bl_ = 0; bl_ < 4; ++bl_) {
                int b = bg2 * 4 + bl_;
                int c1 = s1code[t * NB + b];
                int c2 = s2code[t * NB + b];
                for (int k = tid; k < 640; k += NT) {
                    float v = 0.f;
                    if (k < 256) {
                        if (c2 >= 1000)   v = cohLd(&redh[((size_t)(c2 - 1000) * NB + b) * DN + k]);
                        else if (c2 >= 0) v = bufh[((size_t)b * LN + c2) * DN + k];
                    } else if (k < 512) {
                        int k2 = k - 256;
                        if (c1 >= 1000)   v = cohLd(&redh[((size_t)(c1 - 1000) * NB + b) * DN + k2]);
                        else if (c1 >= 0) v = bufh[((size_t)b * LN + c1) * DN + k2];
                    } else {
                        v = cohLd(&th[((size_t)par2 * NB + b) * TKN + (k - 512)]);
                    }
                    sm.p2.xs2[bl_][k] = v;
                }
            }
            __syncthreads();
            {
                int jj = tid & 15, ks = tid >> 4;     // 16 j x 32 kslices
                int colbase = jgw * 16 + jj;
                float acc[5][4];
                #pragma unroll
                for (int g = 0; g < 5; ++g)
                    #pragma unroll
                    for (int b4 = 0; b4 < 4; ++b4) acc[g][b4] = 0.f;
                int k0 = ks * 20, k1 = k0 + 20;
                const float* const segb[3] = {WLm, WRm, WTm};
                const int segs[4] = {0, 256, 512, 640};
                #pragma unroll
                for (int s = 0; s < 3; ++s) {
                    int lo = k0 > segs[s] ? k0 : segs[s];
                    int hi = k1 < segs[s + 1] ? k1 : segs[s + 1];
                    const float* base = segb[s] + colbase;
                    for (int k = lo; k < hi; ++k) {
                        const float* wrow = base + (size_t)(k - segs[s]) * GR;
                        float x0 = sm.p2.xs2[0][k];
                        float x1 = sm.p2.xs2[1][k];
                        float x2 = sm.p2.xs2[2][k];
                        float x3 = sm.p2.xs2[3][k];
                        #pragma unroll
                        for (int g = 0; g < 5; ++g) {
                            float wv = wrow[g * 256];
                            acc[g][0] += x0 * wv;
                            acc[g][1] += x1 * wv;
                            acc[g][2] += x2 * wv;
                            acc[g][3] += x3 * wv;
                        }
                    }
                }
                #pragma unroll
                for (int b4 = 0; b4 < 4; ++b4)
                    #pragma unroll
                    for (int g = 0; g < 5; ++g)
                        sm.p2.part2[b4][g][ks][jj] = acc[g][b4];
            }
            __syncthreads();
            if (tid < 320) {
                int g = tid >> 6, r = tid & 63;
                int bl_ = r >> 4, jj = r & 15;
                float s = 0.f;
                #pragma unroll
                for (int ks = 0; ks < 32; ++ks) s += sm.p2.part2[bl_][g][ks][jj];
                sm.p2.gsum2[bl_][g][jj] = s;
            }
            __syncthreads();
            if (tid < 64) {
                int bl_ = tid >> 4, jj = tid & 15;
                int b = bg2 * 4 + bl_;
                int wk = wkA[t * NB + b];
                if (wk >= 0) {
                    int j = jgw * 16 + jj;
                    float ga  = sm.p2.gsum2[bl_][0][jj] + bLv[0 * 256 + j];
                    float gi  = sm.p2.gsum2[bl_][1][jj] + bLv[1 * 256 + j];
                    float gf1 = sm.p2.gsum2[bl_][2][jj] + bLv[2 * 256 + j];
                    float gf2 = sm.p2.gsum2[bl_][3][jj] + bLv[3 * 256 + j];
                    float go  = sm.p2.gsum2[bl_][4][jj] + bLv[4 * 256 + j];
                    int c1 = s1code[t * NB + b], c2 = s2code[t * NB + b];
                    float s2cv = (c2 == -1) ? 0.f
                                : ((c2 >= 1000) ? redc[((size_t)(c2 - 1000) * NB + b) * DN + j]  // owner-stable
                                                : bufc[((size_t)b * LN + c2) * DN + j]);
                    float s1cv = (c1 == -1) ? 0.f
                                : ((c1 >= 1000) ? redc[((size_t)(c1 - 1000) * NB + b) * DN + j]
                                                : bufc[((size_t)b * LN + c1) * DN + j]);
                    float cc = tanhf(ga) * sigf(gi) + sigf(gf1) * s2cv + sigf(gf2) * s1cv;
                    float hh = sigf(go) * tanhf(cc);
                    cohSt(&redh[((size_t)wk * NB + b) * DN + j], hh);   // cross-WG
                    redc[((size_t)wk * NB + b) * DN + j] = cc;          // owner-stable
                }
            }
            gbar(cnt, flag, ph);   // barrier C: redh visible
        }
    }

    // ===== final output: P2-owner (b,j) writes its slice; last barrier covers =====
    if (tid < 64) {
        int bl_ = tid >> 4, jj = tid & 15;
        int b = bg2 * 4 + bl_;
        int j = jgw * 16 + jj;
        int c = fcode[b];
        float h = 0.f, cv = 0.f;
        if (c >= 1000) {
            h  = cohLd(&redh[((size_t)(c - 1000) * NB + b) * DN + j]);
            cv = redc[((size_t)(c - 1000) * NB + b) * DN + j];
        } else if (c >= 0) {
            h  = bufh[((size_t)b * LN + c) * DN + j];
            cv = bufc[((size_t)b * LN + c) * DN + j];
        }
        out[(size_t)b * 2 * DN + j]      = h;
        out[(size_t)b * 2 * DN + DN + j] = cv;
    }
}

extern "C" void kernel_launch(void* const* d_in, const int* in_sizes, int n_in,
                              void* d_out, int out_size, void* d_ws, size_t ws_size,
                              hipStream_t stream) {
    const float* bufh = (const float*)d_in[0];
    const float* bufc = (const float*)d_in[1];
    const float* Wb   = (const float*)d_in[2];
    const float* W1   = (const float*)d_in[3];
    const float* W2   = (const float*)d_in[4];
    const float* Wl   = (const float*)d_in[5];
    const float* blv  = (const float*)d_in[6];
    const float* WLm  = (const float*)d_in[7];
    const float* bLv  = (const float*)d_in[8];
    const float* WR   = (const float*)d_in[9];
    const float* WT   = (const float*)d_in[10];
    const int* trans  = (const int*)d_in[11];
    float* out = (float*)d_out;

    char* p = (char*)d_ws;
    auto carve = [&](size_t bytes) -> char* {
        char* r = p;
        p += (bytes + 255) & ~(size_t)255;
        return r;
    };
    int* tbcode = (int*)carve((size_t)TN * NB * 4);
    int* s1code = (int*)carve((size_t)TN * NB * 4);
    int* s2code = (int*)carve((size_t)TN * NB * 4);
    int* wkA    = (int*)carve((size_t)TN * NB * 4);
    int* fcode  = (int*)carve((size_t)NB * 4);
    int* anyred = (int*)carve((size_t)TN * 4);
    float* th   = (float*)carve((size_t)2 * NB * TKN * 4);
    float* tc   = (float*)carve((size_t)2 * NB * TKN * 4);
    float* redh = (float*)carve((size_t)TN * NB * DN * 4);
    float* redc = (float*)carve((size_t)TN * NB * DN * 4);
    unsigned* cnt  = (unsigned*)carve(512);
    unsigned* flag = cnt + 64;   // separate 256B-aligned line

    hipMemsetAsync(th, 0, (size_t)2 * NB * TKN * 4, stream);
    hipMemsetAsync(tc, 0, (size_t)2 * NB * TKN * 4, stream);
    hipMemsetAsync(cnt, 0, 512, stream);

    k_sched<<<1, 64, 0, stream>>>(trans, tbcode, s1code, s2code, wkA, fcode, anyred);
    k_spinn<<<NWG, NT, 0, stream>>>(bufh, bufc, Wb, W1, W2, Wl, blv,
                                    WLm, bLv, WR, WT,
                                    tbcode, s1code, s2code, wkA, fcode, anyred,
                                    th, tc, redh, redc, cnt, flag, out);
}

// Round 6
// 1946.454 us; speedup vs baseline: 3.7511x; 1.0750x over previous
//
#include <hip/hip_runtime.h>
#include <cstdint>
#include <cstddef>

#define NB 64      // batch
#define LN 48      // buffer length
#define DN 256     // hidden dim
#define TKN 128    // tracker dim
#define TN 95      // steps = 2L-1
#define GA 512     // 4*TK
#define GR 1280    // 5*D
#define NWG 256
#define NT 512

__device__ __forceinline__ float sigf(float x) { return 1.0f / (1.0f + expf(-x)); }

// coherent (sc1) scalar access — bypasses non-coherent per-XCD L2
__device__ __forceinline__ float cohLd(const float* p) {
    return __hip_atomic_load(p, __ATOMIC_RELAXED, __HIP_MEMORY_SCOPE_AGENT);
}
__device__ __forceinline__ void cohSt(float* p, float v) {
    __hip_atomic_store(p, v, __ATOMIC_RELAXED, __HIP_MEMORY_SCOPE_AGENT);
}
__device__ __forceinline__ unsigned cohLdU(const unsigned* p) {
    return __hip_atomic_load(p, __ATOMIC_RELAXED, __HIP_MEMORY_SCOPE_AGENT);
}
__device__ __forceinline__ void cohStU(unsigned* p, unsigned v) {
    __hip_atomic_store(p, v, __ATOMIC_RELAXED, __HIP_MEMORY_SCOPE_AGENT);
}

// contention-free grid barrier:
//   arrival  = relaxed store to a private slot (64B apart — no shared-line RMW)
//   watcher  = WG0 threads 0..255 each poll one slot, then thread0 publishes flag
//   everyone else spins read-only on flag.
// __syncthreads() drains vmcnt(0) before s_barrier, so all sc1 data stores are at
// the coherence point before the arrival store issues (scheme verified r4/r5).
__device__ __forceinline__ void gbar(unsigned* slots, unsigned* flag, unsigned& ph) {
    __syncthreads();
    ph += 1;
    if (blockIdx.x == 0) {
        if (threadIdx.x == 0) cohStU(&slots[0], ph);
        if (threadIdx.x < NWG) {
            while (cohLdU(&slots[threadIdx.x * 16]) < ph)
                __builtin_amdgcn_s_sleep(1);
        }
        __syncthreads();
        if (threadIdx.x == 0) cohStU(flag, ph);
        asm volatile("" ::: "memory");
        __syncthreads();
    } else {
        if (threadIdx.x == 0) {
            cohStU(&slots[blockIdx.x * 16], ph);
            while (cohLdU(flag) < ph)
                __builtin_amdgcn_s_sleep(1);
        }
        asm volatile("" ::: "memory");
        __syncthreads();
    }
}

// ---------------- schedule builder: 1 wg, 64 threads (one per batch) --------
// tag codes: -1 = zeros, 0..47 = BUF idx, 1000+k = RED k
__global__ void k_sched(const int* __restrict__ trans,
                        int* __restrict__ tbcode, int* __restrict__ s1code,
                        int* __restrict__ s2code, int* __restrict__ wkA,
                        int* __restrict__ fcode, int* __restrict__ anyred) {
    __shared__ int tg[NB][LN];
    int b = threadIdx.x;
    if (b >= NB) return;
    for (int i = 0; i < LN; ++i) tg[b][i] = -1;
    int sp = 0, bp = 0, k = 0;
    for (int t = 0; t < TN; ++t) {
        int tr = trans[b * TN + t];
        int shift = (tr == 0);
        int tb = (bp < LN) ? bp : -1;
        tbcode[t * NB + b] = tb;
        int i1 = sp - 1; if (i1 < 0) i1 = 0; if (i1 > LN - 1) i1 = LN - 1;
        int i2 = sp - 2; if (i2 < 0) i2 = 0; if (i2 > LN - 1) i2 = LN - 1;
        s1code[t * NB + b] = (sp >= 1) ? tg[b][i1] : -1;
        s2code[t * NB + b] = (sp >= 2) ? tg[b][i2] : -1;
        int wk_t;
        if (shift) {
            wk_t = -1;
            if (sp >= 0 && sp < LN) tg[b][sp] = tb;
            sp = sp + 1;
            bp = bp + 1;
        } else {
            wk_t = k;
            int pos = sp - 2; if (pos < 0) pos = 0;
            if (pos < LN) tg[b][pos] = 1000 + k;
            k++;
            sp = sp - 1; if (sp < 0) sp = 0;
        }
        wkA[t * NB + b] = wk_t;
        unsigned long long m = __ballot(wk_t >= 0);
        if (b == 0) anyred[t] = (m != 0ull) ? 1 : 0;
    }
    int fi = sp - 1; if (fi < 0) fi = 0; if (fi > LN - 1) fi = LN - 1;
    fcode[b] = tg[b][fi];
}

// ---------------- persistent full-scan kernel -------------------------------
__global__ __launch_bounds__(NT, 1) void k_spinn(
    const float* __restrict__ bufh, const float* __restrict__ bufc,
    const float* __restrict__ Wb, const float* __restrict__ W1,
    const float* __restrict__ W2, const float* __restrict__ Wl,
    const float* __restrict__ blv,
    const float* __restrict__ WLm, const float* __restrict__ bLv,
    const float* __restrict__ WRm, const float* __restrict__ WTm,
    const int* __restrict__ tbcode, const int* __restrict__ s1code,
    const int* __restrict__ s2code, const int* __restrict__ wkA,
    const int* __restrict__ fcode, const int* __restrict__ anyred,
    float* __restrict__ th, float* __restrict__ tc,
    float* __restrict__ redh, float* __restrict__ redc,
    unsigned* __restrict__ slots, unsigned* __restrict__ flag,
    float* __restrict__ out) {
    const int wg = blockIdx.x;
    const int tid = threadIdx.x;
    const int lane = tid & 63;
    const int w = tid >> 6;                 // 8 waves
    unsigned ph = 0;

    // XCD-pinned decompositions (xcd = wg & 7 — perf heuristic only)
    const int xcd = wg & 7;
    const int u = wg >> 3;                  // 0..31
    // P1: 8 bg (8 b) x 32 jg (4 tracker-j x 4 quadrants = 16 cols); jg pinned to xcd
    const int bg1 = u & 7;
    const int jg1 = xcd * 4 + (u >> 3);     // 0..31
    // P2: 16 bg (4 b) x 16 jgw (16 j x 5 gates = 80 cols); jgw pinned to xcd
    const int bg2 = u >> 1;                 // 0..15
    const int jgw = (u & 1) + 2 * xcd;      // 0..15

    __shared__ union {
        struct { float xs[8][900]; float part1[8][64][2]; float gsum[8][16]; } p1;  // 900: stride%32=4
        struct { float xs2[4][640]; float part2[4][5][33][16]; float gsum2[4][5][16]; } p2;
    } sm;

    for (int t = 0; t < TN; ++t) {
        const int par = t & 1;
        // ================= P1: gates GEMM + tracker LSTM =================
        for (int bl_ = 0; bl_ < 8; ++bl_) {
            int b = bg1 * 8 + bl_;
            int ctb = tbcode[t * NB + b];
            int c1  = s1code[t * NB + b];
            int c2  = s2code[t * NB + b];
            for (int k = tid; k < 896; k += NT) {
                float v = 0.f;
                if (k < 256) {
                    if (ctb >= 0) v = bufh[((size_t)b * LN + ctb) * DN + k];
                } else if (k < 512) {
                    int kk = k - 256;
                    if (c1 >= 1000)     v = cohLd(&redh[((size_t)(c1 - 1000) * NB + b) * DN + kk]);
                    else if (c1 >= 0)   v = bufh[((size_t)b * LN + c1) * DN + kk];
                } else if (k < 768) {
                    int kk = k - 512;
                    if (c2 >= 1000)     v = cohLd(&redh[((size_t)(c2 - 1000) * NB + b) * DN + kk]);
                    else if (c2 >= 0)   v = bufh[((size_t)b * LN + c2) * DN + kk];
                } else {
                    v = cohLd(&th[((size_t)par * NB + b) * TKN + (k - 768)]);
                }
                sm.p1.xs[bl_][k] = v;
            }
        }
        __syncthreads();
        {
            int colL = lane & 15, bh = lane >> 4;     // col 16, b-half 4 (2 b each)
            int q = colL >> 2, jo = colL & 3;
            int col = q * 128 + jg1 * 4 + jo;
            int bl0 = bh * 2, bl1 = bh * 2 + 1;
            float a0 = 0.f, a1 = 0.f;
            int k0 = w * 112, k1 = k0 + 112;
            const float* const segb[4] = {Wb, W1, W2, Wl};
            const int segs[5] = {0, 256, 512, 768, 896};
            #pragma unroll
            for (int s = 0; s < 4; ++s) {
                int lo = k0 > segs[s] ? k0 : segs[s];
                int hi = k1 < segs[s + 1] ? k1 : segs[s + 1];
                const float* base = segb[s] + col;
                #pragma unroll 4
                for (int k = lo; k < hi; ++k) {
                    float wv = base[(size_t)(k - segs[s]) * GA];
                    a0 += sm.p1.xs[bl0][k] * wv;
                    a1 += sm.p1.xs[bl1][k] * wv;
                }
            }
            sm.p1.part1[w][lane][0] = a0;
            sm.p1.part1[w][lane][1] = a1;
        }
        __syncthreads();
        if (w == 0) {
            float s0 = 0.f, s1 = 0.f;
            #pragma unroll
            for (int ww = 0; ww < 8; ++ww) { s0 += sm.p1.part1[ww][lane][0]; s1 += sm.p1.part1[ww][lane][1]; }
            int colL = lane & 15, bh = lane >> 4;
            int q = colL >> 2, jo = colL & 3;
            int col = q * 128 + jg1 * 4 + jo;
            if (t > 0) { float bv = blv[col]; s0 += bv; s1 += bv; }
            sm.p1.gsum[bh * 2][colL]     = s0;
            sm.p1.gsum[bh * 2 + 1][colL] = s1;
        }
        __syncthreads();
        if (tid < 32) {
            int bloc = tid >> 2, jj4 = tid & 3;
            int b = bg1 * 8 + bloc;
            int j = jg1 * 4 + jj4;
            float a = sm.p1.gsum[bloc][jj4];
            float i = sm.p1.gsum[bloc][4 + jj4];
            float f = sm.p1.gsum[bloc][8 + jj4];
            float o = sm.p1.gsum[bloc][12 + jj4];
            float tco = tc[((size_t)par * NB + b) * TKN + j];       // owner-stable, plain
            float c2v = tanhf(a) * sigf(i) + sigf(f) * tco;
            float h2 = sigf(o) * tanhf(c2v);
            tc[((size_t)(par ^ 1) * NB + b) * TKN + j] = c2v;       // owner-stable, plain
            cohSt(&th[((size_t)(par ^ 1) * NB + b) * TKN + j], h2); // cross-WG
        }
        gbar(slots, flag, ph);   // barrier A: th2 visible

        if (anyred[t]) {
            // ===== P2: full-K rgates GEMM + in-WG TreeLSTM (no partial exchange) =====
            const int par2 = par ^ 1;
            for (int bl_ = 0; bl_ < 4; ++bl_) {
                int b = bg2 * 4 + bl_;
                int c1 = s1code[t * NB + b];
                int c2 = s2code[t * NB + b];
                for (int k = tid; k < 640; k += NT) {
                    float v = 0.f;
                    if (k < 256) {
                        if (c2 >= 1000)   v = cohLd(&redh[((size_t)(c2 - 1000) * NB + b) * DN + k]);
                        else if (c2 >= 0) v = bufh[((size_t)b * LN + c2) * DN + k];
                    } else if (k < 512) {
                        int k2 = k - 256;
                        if (c1 >= 1000)   v = cohLd(&redh[((size_t)(c1 - 1000) * NB + b) * DN + k2]);
                        else if (c1 >= 0) v = bufh[((size_t)b * LN + c1) * DN + k2];
                    } else {
                        v = cohLd(&th[((size_t)par2 * NB + b) * TKN + (k - 512)]);
                    }
                    sm.p2.xs2[bl_][k] = v;
                }
            }
            __syncthreads();
            {
                int jj = tid & 15, ks = tid >> 4;     // 16 j x 32 kslices
                int colbase = jgw * 16 + jj;
                float acc[5][4];
                #pragma unroll
                for (int g = 0; g < 5; ++g)
                    #pragma unroll
                    for (int b4 = 0; b4 < 4; ++b4) acc[g][b4] = 0.f;
                int k0 = ks * 20, k1 = k0 + 20;
                const float* const segb[3] = {WLm, WRm, WTm};
                const int segs[4] = {0, 256, 512, 640};
                #pragma unroll
                for (int s = 0; s < 3; ++s) {
                    int lo = k0 > segs[s] ? k0 : segs[s];
                    int hi = k1 < segs[s + 1] ? k1 : segs[s + 1];
                    const float* base = segb[s] + colbase;
                    for (int k = lo; k < hi; ++k) {
                        const float* wrow = base + (size_t)(k - segs[s]) * GR;
                        float x0 = sm.p2.xs2[0][k];
                        float x1 = sm.p2.xs2[1][k];
                        float x2 = sm.p2.xs2[2][k];
                        float x3 = sm.p2.xs2[3][k];
                        #pragma unroll
                        for (int g = 0; g < 5; ++g) {
                            float wv = wrow[g * 256];
                            acc[g][0] += x0 * wv;
                            acc[g][1] += x1 * wv;
                            acc[g][2] += x2 * wv;
                            acc[g][3] += x3 * wv;
                        }
                    }
                }
                #pragma unroll
                for (int b4 = 0; b4 < 4; ++b4)
                    #pragma unroll
                    for (int g = 0; g < 5; ++g)
                        sm.p2.part2[b4][g][ks][jj] = acc[g][b4];
            }
            __syncthreads();
            if (tid < 320) {
                int g = tid >> 6, r = tid & 63;
                int bl_ = r >> 4, jj = r & 15;
                float s = 0.f;
                #pragma unroll
                for (int ks = 0; ks < 32; ++ks) s += sm.p2.part2[bl_][g][ks][jj];
                sm.p2.gsum2[bl_][g][jj] = s;
            }
            __syncthreads();
            if (tid < 64) {
                int bl_ = tid >> 4, jj = tid & 15;
                int b = bg2 * 4 + bl_;
                int wk = wkA[t * NB + b];
                if (wk >= 0) {
                    int j = jgw * 16 + jj;
                    float ga  = sm.p2.gsum2[bl_][0][jj] + bLv[0 * 256 + j];
                    float gi  = sm.p2.gsum2[bl_][1][jj] + bLv[1 * 256 + j];
                    float gf1 = sm.p2.gsum2[bl_][2][jj] + bLv[2 * 256 + j];
                    float gf2 = sm.p2.gsum2[bl_][3][jj] + bLv[3 * 256 + j];
                    float go  = sm.p2.gsum2[bl_][4][jj] + bLv[4 * 256 + j];
                    int c1 = s1code[t * NB + b], c2 = s2code[t * NB + b];
                    float s2cv = (c2 == -1) ? 0.f
                                : ((c2 >= 1000) ? redc[((size_t)(c2 - 1000) * NB + b) * DN + j]  // owner-stable
                                                : bufc[((size_t)b * LN + c2) * DN + j]);
                    float s1cv = (c1 == -1) ? 0.f
                                : ((c1 >= 1000) ? redc[((size_t)(c1 - 1000) * NB + b) * DN + j]
                                                : bufc[((size_t)b * LN + c1) * DN + j]);
                    float cc = tanhf(ga) * sigf(gi) + sigf(gf1) * s2cv + sigf(gf2) * s1cv;
                    float hh = sigf(go) * tanhf(cc);
                    cohSt(&redh[((size_t)wk * NB + b) * DN + j], hh);   // cross-WG
                    redc[((size_t)wk * NB + b) * DN + j] = cc;          // owner-stable
                }
            }
            gbar(slots, flag, ph);   // barrier C: redh visible
        }
    }

    // ===== final output: P2-owner (b,j) writes its slice; last barrier covers =====
    if (tid < 64) {
        int bl_ = tid >> 4, jj = tid & 15;
        int b = bg2 * 4 + bl_;
        int j = jgw * 16 + jj;
        int c = fcode[b];
        float h = 0.f, cv = 0.f;
        if (c >= 1000) {
            h  = cohLd(&redh[((size_t)(c - 1000) * NB + b) * DN + j]);
            cv = redc[((size_t)(c - 1000) * NB + b) * DN + j];
        } else if (c >= 0) {
            h  = bufh[((size_t)b * LN + c) * DN + j];
            cv = bufc[((size_t)b * LN + c) * DN + j];
        }
        out[(size_t)b * 2 * DN + j]      = h;
        out[(size_t)b * 2 * DN + DN + j] = cv;
    }
}

extern "C" void kernel_launch(void* const* d_in, const int* in_sizes, int n_in,
                              void* d_out, int out_size, void* d_ws, size_t ws_size,
                              hipStream_t stream) {
    const float* bufh = (const float*)d_in[0];
    const float* bufc = (const float*)d_in[1];
    const float* Wb   = (const float*)d_in[2];
    const float* W1   = (const float*)d_in[3];
    const float* W2   = (const float*)d_in[4];
    const float* Wl   = (const float*)d_in[5];
    const float* blv  = (const float*)d_in[6];
    const float* WLm  = (const float*)d_in[7];
    const float* bLv  = (const float*)d_in[8];
    const float* WR   = (const float*)d_in[9];
    const float* WT   = (const float*)d_in[10];
    const int* trans  = (const int*)d_in[11];
    float* out = (float*)d_out;

    char* p = (char*)d_ws;
    auto carve = [&](size_t bytes) -> char* {
        char* r = p;
        p += (bytes + 255) & ~(size_t)255;
        return r;
    };
    int* tbcode = (int*)carve((size_t)TN * NB * 4);
    int* s1code = (int*)carve((size_t)TN * NB * 4);
    int* s2code = (int*)carve((size_t)TN * NB * 4);
    int* wkA    = (int*)carve((size_t)TN * NB * 4);
    int* fcode  = (int*)carve((size_t)NB * 4);
    int* anyred = (int*)carve((size_t)TN * 4);
    float* th   = (float*)carve((size_t)2 * NB * TKN * 4);
    float* tc   = (float*)carve((size_t)2 * NB * TKN * 4);
    float* redh = (float*)carve((size_t)TN * NB * DN * 4);
    float* redc = (float*)carve((size_t)TN * NB * DN * 4);
    unsigned* slots = (unsigned*)carve((size_t)NWG * 16 * 4);   // 64B-spaced arrival slots
    unsigned* flag  = (unsigned*)carve(256);

    hipMemsetAsync(th, 0, (size_t)2 * NB * TKN * 4, stream);
    hipMemsetAsync(tc, 0, (size_t)2 * NB * TKN * 4, stream);
    hipMemsetAsync(slots, 0, (size_t)NWG * 16 * 4, stream);
    hipMemsetAsync(flag, 0, 256, stream);

    k_sched<<<1, 64, 0, stream>>>(trans, tbcode, s1code, s2code, wkA, fcode, anyred);
    k_spinn<<<NWG, NT, 0, stream>>>(bufh, bufc, Wb, W1, W2, Wl, blv,
                                    WLm, bLv, WR, WT,
                                    tbcode, s1code, s2code, wkA, fcode, anyred,
                                    th, tc, redh, redc, slots, flag, out);
}

// Round 7
// 1636.741 us; speedup vs baseline: 4.4610x; 1.1892x over previous
//
#include <hip/hip_runtime.h>
#include <cstdint>
#include <cstddef>

#define NB 64      // batch
#define LN 48      // buffer length
#define DN 256     // hidden dim
#define TKN 128    // tracker dim
#define TN 95      // steps = 2L-1
#define RMAX 48    // max reduces per batch (L-1 = 47)
#define GA 512     // 4*TK
#define GR 1280    // 5*D
#define NWG 256
#define NT 512

__device__ __forceinline__ float sigf(float x) { return 1.0f / (1.0f + expf(-x)); }

// coherent (sc1) scalar access — bypasses non-coherent per-XCD L2
__device__ __forceinline__ float cohLd(const float* p) {
    return __hip_atomic_load(p, __ATOMIC_RELAXED, __HIP_MEMORY_SCOPE_AGENT);
}
__device__ __forceinline__ void cohSt(float* p, float v) {
    __hip_atomic_store(p, v, __ATOMIC_RELAXED, __HIP_MEMORY_SCOPE_AGENT);
}
__device__ __forceinline__ unsigned cohLdU(const unsigned* p) {
    return __hip_atomic_load(p, __ATOMIC_RELAXED, __HIP_MEMORY_SCOPE_AGENT);
}
__device__ __forceinline__ void cohStU(unsigned* p, unsigned v) {
    __hip_atomic_store(p, v, __ATOMIC_RELAXED, __HIP_MEMORY_SCOPE_AGENT);
}

// contention-free grid barrier (verified r6): arrival store to private slot,
// WG0 watcher polls slots then publishes flag; others spin read-only on flag.
__device__ __forceinline__ void gbar(unsigned* slots, unsigned* flag, unsigned& ph) {
    __syncthreads();
    ph += 1;
    if (blockIdx.x == 0) {
        if (threadIdx.x == 0) cohStU(&slots[0], ph);
        if (threadIdx.x < NWG) {
            while (cohLdU(&slots[threadIdx.x * 16]) < ph)
                __builtin_amdgcn_s_sleep(1);
        }
        __syncthreads();
        if (threadIdx.x == 0) cohStU(flag, ph);
        asm volatile("" ::: "memory");
        __syncthreads();
    } else {
        if (threadIdx.x == 0) {
            cohStU(&slots[blockIdx.x * 16], ph);
            while (cohLdU(flag) < ph)
                __builtin_amdgcn_s_sleep(1);
        }
        asm volatile("" ::: "memory");
        __syncthreads();
    }
}

// ---------------- schedule builder (verified r1-r6) -------------------------
__global__ void k_sched(const int* __restrict__ trans,
                        int* __restrict__ tbcode, int* __restrict__ s1code,
                        int* __restrict__ s2code, int* __restrict__ wkA,
                        int* __restrict__ fcode, int* __restrict__ anyred) {
    __shared__ int tg[NB][LN];
    int b = threadIdx.x;
    if (b >= NB) return;
    for (int i = 0; i < LN; ++i) tg[b][i] = -1;
    int sp = 0, bp = 0, k = 0;
    for (int t = 0; t < TN; ++t) {
        int tr = trans[b * TN + t];
        int shift = (tr == 0);
        int tb = (bp < LN) ? bp : -1;
        tbcode[t * NB + b] = tb;
        int i1 = sp - 1; if (i1 < 0) i1 = 0; if (i1 > LN - 1) i1 = LN - 1;
        int i2 = sp - 2; if (i2 < 0) i2 = 0; if (i2 > LN - 1) i2 = LN - 1;
        s1code[t * NB + b] = (sp >= 1) ? tg[b][i1] : -1;
        s2code[t * NB + b] = (sp >= 2) ? tg[b][i2] : -1;
        int wk_t;
        if (shift) {
            wk_t = -1;
            if (sp >= 0 && sp < LN) tg[b][sp] = tb;
            sp = sp + 1;
            bp = bp + 1;
        } else {
            wk_t = k;
            int pos = sp - 2; if (pos < 0) pos = 0;
            if (pos < LN) tg[b][pos] = 1000 + k;
            k++;
            sp = sp - 1; if (sp < 0) sp = 0;
        }
        wkA[t * NB + b] = wk_t;
        unsigned long long m = __ballot(wk_t >= 0);
        if (b == 0) anyred[t] = (m != 0ull) ? 1 : 0;
    }
    int fi = sp - 1; if (fi < 0) fi = 0; if (fi > LN - 1) fi = LN - 1;
    fcode[b] = tg[b][fi];
}

// ---------------- P1 weight repack: WA[k][j*4+gate] -------------------------
__global__ __launch_bounds__(256) void k_pack(
    const float* __restrict__ Wb, const float* __restrict__ W1,
    const float* __restrict__ W2, const float* __restrict__ Wl,
    const float* __restrict__ blv,
    float* __restrict__ WA, float* __restrict__ blA) {
    int idx = blockIdx.x * 256 + threadIdx.x;
    if (idx < 896 * 512) {
        int k = idx >> 9, cp = idx & 511;
        int j = cp >> 2, q = cp & 3;
        int sc = q * 128 + j;
        float v;
        if (k < 256)      v = Wb[(size_t)k * GA + sc];
        else if (k < 512) v = W1[(size_t)(k - 256) * GA + sc];
        else if (k < 768) v = W2[(size_t)(k - 512) * GA + sc];
        else              v = Wl[(size_t)(k - 768) * GA + sc];
        WA[idx] = v;
    }
    if (idx < 512) {
        int j = idx >> 2, q = idx & 3;
        blA[idx] = blv[q * 128 + j];
    }
}

// ---------------- persistent full-scan kernel -------------------------------
__global__ __launch_bounds__(NT, 1) void k_spinn(
    const float* __restrict__ bufh, const float* __restrict__ bufc,
    const float* __restrict__ WA, const float* __restrict__ blA,
    const float* __restrict__ WLm, const float* __restrict__ bLv,
    const float* __restrict__ WRm, const float* __restrict__ WTm,
    const int* __restrict__ tbcode, const int* __restrict__ s1code,
    const int* __restrict__ s2code, const int* __restrict__ wkA,
    const int* __restrict__ fcode, const int* __restrict__ anyred,
    float* __restrict__ th, float* __restrict__ tc,
    float* __restrict__ redh, float* __restrict__ redc,
    unsigned* __restrict__ slots, unsigned* __restrict__ flag,
    float* __restrict__ out) {
    const int wg = blockIdx.x;
    const int tid = threadIdx.x;
    const int lane = tid & 63;
    const int w = tid >> 6;                 // 8 waves
    unsigned ph = 0;

    const int xcd = wg & 7;
    const int u = wg >> 3;                  // 0..31
    // P1: jg = xcd (16 tracker-j = 64 packed cols, slice 229KB L2-pinned/XCD); bg1 = u (2 b)
    const int jg = xcd;
    const int bg1 = u;                      // 0..31
    // P2: 16 bg (4 b) x 16 jgw (16 j x 5 gates); jgw pinned to xcd (verified r6)
    const int bg2 = u >> 1;                 // 0..15
    const int jgw = (u & 1) + 2 * xcd;      // 0..15

    __shared__ union {
        struct { float xs[2][896]; float4 part4[32][16][2]; float gsum[2][64]; } p1;
        struct { float xs2[4][640]; float part2[4][5][33][16]; float gsum2[4][5][16]; } p2;
    } sm;

    for (int t = 0; t < TN; ++t) {
        const int par = t & 1;
        // ================= P1: gates GEMM + tracker LSTM =================
        // stage xs[2][896] as 448 float4 groups, one per thread (batched loads)
        if (tid < 448) {
            int row = tid & 1;              // batch-local
            int k0 = (tid >> 1) * 4;        // 0..892
            int b = bg1 * 2 + row;
            float4 v = {0.f, 0.f, 0.f, 0.f};
            if (k0 < 256) {
                int c = tbcode[t * NB + b];
                if (c >= 0) v = *(const float4*)&bufh[((size_t)b * LN + c) * DN + k0];
            } else if (k0 < 512) {
                int c = s1code[t * NB + b];
                int kk = k0 - 256;
                if (c >= 1000) {
                    const float* p = &redh[((size_t)(c - 1000) * NB + b) * DN + kk];
                    v.x = cohLd(p); v.y = cohLd(p + 1); v.z = cohLd(p + 2); v.w = cohLd(p + 3);
                } else if (c >= 0) v = *(const float4*)&bufh[((size_t)b * LN + c) * DN + kk];
            } else if (k0 < 768) {
                int c = s2code[t * NB + b];
                int kk = k0 - 512;
                if (c >= 1000) {
                    const float* p = &redh[((size_t)(c - 1000) * NB + b) * DN + kk];
                    v.x = cohLd(p); v.y = cohLd(p + 1); v.z = cohLd(p + 2); v.w = cohLd(p + 3);
                } else if (c >= 0) v = *(const float4*)&bufh[((size_t)b * LN + c) * DN + kk];
            } else {
                const float* p = &th[((size_t)par * NB + b) * TKN + (k0 - 768)];
                v.x = cohLd(p); v.y = cohLd(p + 1); v.z = cohLd(p + 2); v.w = cohLd(p + 3);
            }
            *(float4*)&sm.p1.xs[row][k0] = v;
        }
        __syncthreads();
        {
            // wave: 16 lanes x float4 cols (64 contiguous packed cols) x 4 k-subslices
            int c4 = lane & 15, ks = lane >> 4;
            int kbase = w * 112 + ks * 28;
            const float4* wp = (const float4*)(WA + (size_t)kbase * 512 + jg * 64) + c4;
            float4 a0 = {0.f, 0.f, 0.f, 0.f}, a1 = {0.f, 0.f, 0.f, 0.f};
            #pragma unroll 4
            for (int k = 0; k < 28; ++k) {
                float4 wv = wp[(size_t)k * 128];
                float x0 = sm.p1.xs[0][kbase + k];
                float x1 = sm.p1.xs[1][kbase + k];
                a0.x += x0 * wv.x; a0.y += x0 * wv.y; a0.z += x0 * wv.z; a0.w += x0 * wv.w;
                a1.x += x1 * wv.x; a1.y += x1 * wv.y; a1.z += x1 * wv.z; a1.w += x1 * wv.w;
            }
            int s = w * 4 + ks;
            sm.p1.part4[s][c4][0] = a0;
            sm.p1.part4[s][c4][1] = a1;
        }
        __syncthreads();
        if (tid < 128) {
            int bl_ = tid >> 6, cl = tid & 63;
            int c4 = cl >> 2, ci = cl & 3;
            float s = 0.f;
            #pragma unroll
            for (int ss = 0; ss < 32; ++ss) {
                const float4& p4 = sm.p1.part4[ss][c4][bl_];
                s += (ci == 0) ? p4.x : (ci == 1) ? p4.y : (ci == 2) ? p4.z : p4.w;
            }
            if (t > 0) s += blA[jg * 64 + cl];
            sm.p1.gsum[bl_][cl] = s;
        }
        __syncthreads();
        if (tid < 32) {
            int bl_ = tid >> 4, jj = tid & 15;
            int b = bg1 * 2 + bl_;
            int j = jg * 16 + jj;
            float4 g4 = *(const float4*)&sm.p1.gsum[bl_][jj * 4];  // a,i,f,o adjacent
            float tco = tc[((size_t)par * NB + b) * TKN + j];       // owner-stable
            float c2v = tanhf(g4.x) * sigf(g4.y) + sigf(g4.z) * tco;
            float h2 = sigf(g4.w) * tanhf(c2v);
            tc[((size_t)(par ^ 1) * NB + b) * TKN + j] = c2v;       // owner-stable
            cohSt(&th[((size_t)(par ^ 1) * NB + b) * TKN + j], h2); // cross-WG
        }
        gbar(slots, flag, ph);   // barrier A: th2 visible

        if (anyred[t]) {
            // ===== P2: full-K rgates GEMM + in-WG TreeLSTM =====
            const int par2 = par ^ 1;
            // stage xs2[4][640] as 640 float4 groups (512 + 128 extra)
            {
                int g = tid;
                int row = g & 3, k0 = (g >> 2) * 4;
                int b = bg2 * 4 + row;
                float4 v = {0.f, 0.f, 0.f, 0.f};
                if (k0 < 256) {
                    int c = s2code[t * NB + b];
                    if (c >= 1000) {
                        const float* p = &redh[((size_t)(c - 1000) * NB + b) * DN + k0];
                        v.x = cohLd(p); v.y = cohLd(p + 1); v.z = cohLd(p + 2); v.w = cohLd(p + 3);
                    } else if (c >= 0) v = *(const float4*)&bufh[((size_t)b * LN + c) * DN + k0];
                } else if (k0 < 512) {
                    int c = s1code[t * NB + b];
                    int kk = k0 - 256;
                    if (c >= 1000) {
                        const float* p = &redh[((size_t)(c - 1000) * NB + b) * DN + kk];
                        v.x = cohLd(p); v.y = cohLd(p + 1); v.z = cohLd(p + 2); v.w = cohLd(p + 3);
                    } else if (c >= 0) v = *(const float4*)&bufh[((size_t)b * LN + c) * DN + kk];
                } else {
                    const float* p = &th[((size_t)par2 * NB + b) * TKN + (k0 - 512)];
                    v.x = cohLd(p); v.y = cohLd(p + 1); v.z = cohLd(p + 2); v.w = cohLd(p + 3);
                }
                *(float4*)&sm.p2.xs2[row][k0] = v;
                if (tid < 128) {
                    int g2 = 512 + tid;
                    int row2 = g2 & 3, k02 = (g2 >> 2) * 4;   // th segment
                    int b2 = bg2 * 4 + row2;
                    const float* p = &th[((size_t)par2 * NB + b2) * TKN + (k02 - 512)];
                    float4 v2;
                    v2.x = cohLd(p); v2.y = cohLd(p + 1); v2.z = cohLd(p + 2); v2.w = cohLd(p + 3);
                    *(float4*)&sm.p2.xs2[row2][k02] = v2;
                }
            }
            __syncthreads();
            {
                int jj = tid & 15, ks = tid >> 4;     // 16 j x 32 kslices
                int colbase = jgw * 16 + jj;
                float acc[5][4];
                #pragma unroll
                for (int g = 0; g < 5; ++g)
                    #pragma unroll
                    for (int b4 = 0; b4 < 4; ++b4) acc[g][b4] = 0.f;
                int k0 = ks * 20, k1 = k0 + 20;
                const float* const segb[3] = {WLm, WRm, WTm};
                const int segs[4] = {0, 256, 512, 640};
                #pragma unroll
                for (int s = 0; s < 3; ++s) {
                    int lo = k0 > segs[s] ? k0 : segs[s];
                    int hi = k1 < segs[s + 1] ? k1 : segs[s + 1];
                    const float* base = segb[s] + colbase;
                    #pragma unroll 4
                    for (int k = lo; k < hi; ++k) {
                        const float* wrow = base + (size_t)(k - segs[s]) * GR;
                        float x0 = sm.p2.xs2[0][k];
                        float x1 = sm.p2.xs2[1][k];
                        float x2 = sm.p2.xs2[2][k];
                        float x3 = sm.p2.xs2[3][k];
                        #pragma unroll
                        for (int g = 0; g < 5; ++g) {
                            float wv = wrow[g * 256];
                            acc[g][0] += x0 * wv;
                            acc[g][1] += x1 * wv;
                            acc[g][2] += x2 * wv;
                            acc[g][3] += x3 * wv;
                        }
                    }
                }
                #pragma unroll
                for (int b4 = 0; b4 < 4; ++b4)
                    #pragma unroll
                    for (int g = 0; g < 5; ++g)
                        sm.p2.part2[b4][g][ks][jj] = acc[g][b4];
            }
            __syncthreads();
            if (tid < 320) {
                int g = tid >> 6, r = tid & 63;
                int bl_ = r >> 4, jj = r & 15;
                float s = 0.f;
                #pragma unroll
                for (int ks = 0; ks < 32; ++ks) s += sm.p2.part2[bl_][g][ks][jj];
                sm.p2.gsum2[bl_][g][jj] = s;
            }
            __syncthreads();
            if (tid < 64) {
                int bl_ = tid >> 4, jj = tid & 15;
                int b = bg2 * 4 + bl_;
                int wk = wkA[t * NB + b];
                if (wk >= 0) {
                    int j = jgw * 16 + jj;
                    float ga  = sm.p2.gsum2[bl_][0][jj] + bLv[0 * 256 + j];
                    float gi  = sm.p2.gsum2[bl_][1][jj] + bLv[1 * 256 + j];
                    float gf1 = sm.p2.gsum2[bl_][2][jj] + bLv[2 * 256 + j];
                    float gf2 = sm.p2.gsum2[bl_][3][jj] + bLv[3 * 256 + j];
                    float go  = sm.p2.gsum2[bl_][4][jj] + bLv[4 * 256 + j];
                    int c1 = s1code[t * NB + b], c2 = s2code[t * NB + b];
                    float s2cv = (c2 == -1) ? 0.f
                                : ((c2 >= 1000) ? redc[((size_t)(c2 - 1000) * NB + b) * DN + j]
                                                : bufc[((size_t)b * LN + c2) * DN + j]);
                    float s1cv = (c1 == -1) ? 0.f
                                : ((c1 >= 1000) ? redc[((size_t)(c1 - 1000) * NB + b) * DN + j]
                                                : bufc[((size_t)b * LN + c1) * DN + j]);
                    float cc = tanhf(ga) * sigf(gi) + sigf(gf1) * s2cv + sigf(gf2) * s1cv;
                    float hh = sigf(go) * tanhf(cc);
                    cohSt(&redh[((size_t)wk * NB + b) * DN + j], hh);   // cross-WG
                    redc[((size_t)wk * NB + b) * DN + j] = cc;          // owner-stable
                }
            }
            gbar(slots, flag, ph);   // barrier C: redh visible
        }
    }

    // ===== final output: P2-owner (b,j) writes its slice =====
    if (tid < 64) {
        int bl_ = tid >> 4, jj = tid & 15;
        int b = bg2 * 4 + bl_;
        int j = jgw * 16 + jj;
        int c = fcode[b];
        float h = 0.f, cv = 0.f;
        if (c >= 1000) {
            h  = cohLd(&redh[((size_t)(c - 1000) * NB + b) * DN + j]);
            cv = redc[((size_t)(c - 1000) * NB + b) * DN + j];
        } else if (c >= 0) {
            h  = bufh[((size_t)b * LN + c) * DN + j];
            cv = bufc[((size_t)b * LN + c) * DN + j];
        }
        out[(size_t)b * 2 * DN + j]      = h;
        out[(size_t)b * 2 * DN + DN + j] = cv;
    }
}

extern "C" void kernel_launch(void* const* d_in, const int* in_sizes, int n_in,
                              void* d_out, int out_size, void* d_ws, size_t ws_size,
                              hipStream_t stream) {
    const float* bufh = (const float*)d_in[0];
    const float* bufc = (const float*)d_in[1];
    const float* Wb   = (const float*)d_in[2];
    const float* W1   = (const float*)d_in[3];
    const float* W2   = (const float*)d_in[4];
    const float* Wl   = (const float*)d_in[5];
    const float* blv  = (const float*)d_in[6];
    const float* WLm  = (const float*)d_in[7];
    const float* bLv  = (const float*)d_in[8];
    const float* WR   = (const float*)d_in[9];
    const float* WT   = (const float*)d_in[10];
    const int* trans  = (const int*)d_in[11];
    float* out = (float*)d_out;

    char* p = (char*)d_ws;
    auto carve = [&](size_t bytes) -> char* {
        char* r = p;
        p += (bytes + 255) & ~(size_t)255;
        return r;
    };
    int* tbcode = (int*)carve((size_t)TN * NB * 4);
    int* s1code = (int*)carve((size_t)TN * NB * 4);
    int* s2code = (int*)carve((size_t)TN * NB * 4);
    int* wkA    = (int*)carve((size_t)TN * NB * 4);
    int* fcode  = (int*)carve((size_t)NB * 4);
    int* anyred = (int*)carve((size_t)TN * 4);
    float* th   = (float*)carve((size_t)2 * NB * TKN * 4);
    float* tc   = (float*)carve((size_t)2 * NB * TKN * 4);
    float* redh = (float*)carve((size_t)RMAX * NB * DN * 4);
    float* redc = (float*)carve((size_t)RMAX * NB * DN * 4);
    float* WA   = (float*)carve((size_t)896 * 512 * 4);
    float* blA  = (float*)carve((size_t)512 * 4);
    unsigned* slots = (unsigned*)carve((size_t)NWG * 16 * 4);
    unsigned* flag  = (unsigned*)carve(256);

    hipMemsetAsync(th, 0, (size_t)2 * NB * TKN * 4, stream);
    hipMemsetAsync(tc, 0, (size_t)2 * NB * TKN * 4, stream);
    hipMemsetAsync(slots, 0, (size_t)NWG * 16 * 4, stream);
    hipMemsetAsync(flag, 0, 256, stream);

    k_sched<<<1, 64, 0, stream>>>(trans, tbcode, s1code, s2code, wkA, fcode, anyred);
    k_pack<<<(896 * 512 + 255) / 256, 256, 0, stream>>>(Wb, W1, W2, Wl, blv, WA, blA);
    k_spinn<<<NWG, NT, 0, stream>>>(bufh, bufc, WA, blA,
                                    WLm, bLv, WR, WT,
                                    tbcode, s1code, s2code, wkA, fcode, anyred,
                                    th, tc, redh, redc, slots, flag, out);
}

// Round 8
// 1088.043 us; speedup vs baseline: 6.7106x; 1.5043x over previous
//
#include <hip/hip_runtime.h>
#include <cstdint>
#include <cstddef>

#define NB 64      // batch
#define LN 48      // buffer length
#define DN 256     // hidden dim
#define TKN 128    // tracker dim
#define TN 95      // steps = 2L-1
#define RMAX 48    // max reduces per batch
#define GA 512     // 4*TK
#define GR 1280    // 5*D
#define NWG 256
#define NT 512

__device__ __forceinline__ float sigf(float x) { return 1.0f / (1.0f + expf(-x)); }

// coherent (sc1) scalar access — bypasses non-coherent per-XCD L2
__device__ __forceinline__ float cohLd(const float* p) {
    return __hip_atomic_load(p, __ATOMIC_RELAXED, __HIP_MEMORY_SCOPE_AGENT);
}
__device__ __forceinline__ void cohSt(float* p, float v) {
    __hip_atomic_store(p, v, __ATOMIC_RELAXED, __HIP_MEMORY_SCOPE_AGENT);
}
__device__ __forceinline__ unsigned cohLdU(const unsigned* p) {
    return __hip_atomic_load(p, __ATOMIC_RELAXED, __HIP_MEMORY_SCOPE_AGENT);
}
__device__ __forceinline__ void cohStU(unsigned* p, unsigned v) {
    __hip_atomic_store(p, v, __ATOMIC_RELAXED, __HIP_MEMORY_SCOPE_AGENT);
}

// contention-free grid barrier (verified r6/r7)
__device__ __forceinline__ void gbar(unsigned* slots, unsigned* flag, unsigned& ph) {
    __syncthreads();
    ph += 1;
    if (blockIdx.x == 0) {
        if (threadIdx.x == 0) cohStU(&slots[0], ph);
        if (threadIdx.x < NWG) {
            while (cohLdU(&slots[threadIdx.x * 16]) < ph)
                __builtin_amdgcn_s_sleep(1);
        }
        __syncthreads();
        if (threadIdx.x == 0) cohStU(flag, ph);
        asm volatile("" ::: "memory");
        __syncthreads();
    } else {
        if (threadIdx.x == 0) {
            cohStU(&slots[blockIdx.x * 16], ph);
            while (cohLdU(flag) < ph)
                __builtin_amdgcn_s_sleep(1);
        }
        asm volatile("" ::: "memory");
        __syncthreads();
    }
}

// ---------------- schedule builder (verified r1-r7) -------------------------
__global__ void k_sched(const int* __restrict__ trans,
                        int* __restrict__ tbcode, int* __restrict__ s1code,
                        int* __restrict__ s2code, int* __restrict__ wkA,
                        int* __restrict__ fcode, int* __restrict__ anyred) {
    __shared__ int tg[NB][LN];
    int b = threadIdx.x;
    if (b >= NB) return;
    for (int i = 0; i < LN; ++i) tg[b][i] = -1;
    int sp = 0, bp = 0, k = 0;
    for (int t = 0; t < TN; ++t) {
        int tr = trans[b * TN + t];
        int shift = (tr == 0);
        int tb = (bp < LN) ? bp : -1;
        tbcode[t * NB + b] = tb;
        int i1 = sp - 1; if (i1 < 0) i1 = 0; if (i1 > LN - 1) i1 = LN - 1;
        int i2 = sp - 2; if (i2 < 0) i2 = 0; if (i2 > LN - 1) i2 = LN - 1;
        s1code[t * NB + b] = (sp >= 1) ? tg[b][i1] : -1;
        s2code[t * NB + b] = (sp >= 2) ? tg[b][i2] : -1;
        int wk_t;
        if (shift) {
            wk_t = -1;
            if (sp >= 0 && sp < LN) tg[b][sp] = tb;
            sp = sp + 1;
            bp = bp + 1;
        } else {
            wk_t = k;
            int pos = sp - 2; if (pos < 0) pos = 0;
            if (pos < LN) tg[b][pos] = 1000 + k;
            k++;
            sp = sp - 1; if (sp < 0) sp = 0;
        }
        wkA[t * NB + b] = wk_t;
        unsigned long long m = __ballot(wk_t >= 0);
        if (b == 0) anyred[t] = (m != 0ull) ? 1 : 0;
    }
    int fi = sp - 1; if (fi < 0) fi = 0; if (fi > LN - 1) fi = LN - 1;
    fcode[b] = tg[b][fi];
}

// ---------------- P1 weight repack: WAx[slice][k][64] (slice-major) ---------
// packed col p = slice*64 + c ; j = p>>2, q = p&3 ; src col = q*128 + j
__global__ __launch_bounds__(256) void k_pack_a(
    const float* __restrict__ Wb, const float* __restrict__ W1,
    const float* __restrict__ W2, const float* __restrict__ Wl,
    const float* __restrict__ blv,
    float* __restrict__ WAx, float* __restrict__ blA) {
    int idx = blockIdx.x * 256 + threadIdx.x;
    if (idx < 8 * 896 * 64) {
        int s = idx / (896 * 64);
        int r = idx % (896 * 64);
        int k = r >> 6, c = r & 63;
        int p = s * 64 + c;
        int j = p >> 2, q = p & 3;
        int sc = q * 128 + j;
        float v;
        if (k < 256)      v = Wb[(size_t)k * GA + sc];
        else if (k < 512) v = W1[(size_t)(k - 256) * GA + sc];
        else if (k < 768) v = W2[(size_t)(k - 512) * GA + sc];
        else              v = Wl[(size_t)(k - 768) * GA + sc];
        WAx[idx] = v;
    }
    if (idx < 512) {
        int j = idx >> 2, q = idx & 3;
        blA[idx] = blv[q * 128 + j];
    }
}

// ---------------- P2 weight repack: WBx[slice16][k640][jj16*8] --------------
// slot e<5: gate e, src col = e*256 + slice*16 + jj ; e>=5: pad 0
__global__ __launch_bounds__(256) void k_pack_b(
    const float* __restrict__ WLm, const float* __restrict__ WRm,
    const float* __restrict__ WTm, float* __restrict__ WBx) {
    int idx = blockIdx.x * 256 + threadIdx.x;
    if (idx >= 16 * 640 * 128) return;
    int s = idx / (640 * 128);
    int r = idx % (640 * 128);
    int k = r >> 7, cc = r & 127;
    int jj = cc >> 3, e = cc & 7;
    float v = 0.f;
    if (e < 5) {
        int sc = e * 256 + s * 16 + jj;
        if (k < 256)      v = WLm[(size_t)k * GR + sc];
        else if (k < 512) v = WRm[(size_t)(k - 256) * GR + sc];
        else              v = WTm[(size_t)(k - 512) * GR + sc];
    }
    WBx[idx] = v;
}

// ---------------- persistent full-scan kernel -------------------------------
__global__ __launch_bounds__(NT, 1) void k_spinn(
    const float* __restrict__ bufh, const float* __restrict__ bufc,
    const float* __restrict__ WAx, const float* __restrict__ blA,
    const float* __restrict__ WBx, const float* __restrict__ bLv,
    const int* __restrict__ tbcode, const int* __restrict__ s1code,
    const int* __restrict__ s2code, const int* __restrict__ wkA,
    const int* __restrict__ fcode, const int* __restrict__ anyred,
    float* __restrict__ th, float* __restrict__ tc,
    float* __restrict__ redh, float* __restrict__ redc,
    unsigned* __restrict__ slots, unsigned* __restrict__ flag,
    float* __restrict__ out) {
    const int wg = blockIdx.x;
    const int tid = threadIdx.x;
    const int lane = tid & 63;
    const int w = tid >> 6;                 // 8 waves
    unsigned ph = 0;

    const int xcd = wg & 7;
    const int u = wg >> 3;                  // 0..31
    const int jg = xcd;                     // P1 64-col slice (229KB, L2-pinned/XCD)
    const int bg1 = u;                      // P1: 2 b
    const int bg2 = u >> 1;                 // P2: 4 b
    const int jgw = (u & 1) + 2 * xcd;      // P2 slice 0..15 (320KB; 2/XCD)

    __shared__ float xs[2][896];            // P1 input
    __shared__ float4 part4[16][16][2];     // P1 partials (4 waves x 4 kq)
    __shared__ float gsum[2][64];
    __shared__ float xs2[4][512];           // P2 s-part input
    __shared__ float part2[16][16][21];     // P2 partials, padded
    __shared__ float gsum2[4][5][16];
    __shared__ float xst[4][128];           // th2 for WT part

    for (int t = 0; t < TN; ++t) {
        const int par = t & 1;
        const bool red = anyred[t] != 0;

        // ============ stage: P1 xs (448 f4) + P2s xs2 (512 f4) ============
        int ngroups = red ? 960 : 448;
        for (int g = tid; g < ngroups; g += NT) {
            if (g < 448) {
                int row = g & 1, k0 = (g >> 1) * 4;
                int b = bg1 * 2 + row;
                float4 v = {0.f, 0.f, 0.f, 0.f};
                if (k0 < 256) {
                    int c = tbcode[t * NB + b];
                    if (c >= 0) v = *(const float4*)&bufh[((size_t)b * LN + c) * DN + k0];
                } else if (k0 < 512) {
                    int c = s1code[t * NB + b];
                    int kk = k0 - 256;
                    if (c >= 1000) {
                        const float* p = &redh[((size_t)(c - 1000) * NB + b) * DN + kk];
                        v.x = cohLd(p); v.y = cohLd(p + 1); v.z = cohLd(p + 2); v.w = cohLd(p + 3);
                    } else if (c >= 0) v = *(const float4*)&bufh[((size_t)b * LN + c) * DN + kk];
                } else if (k0 < 768) {
                    int c = s2code[t * NB + b];
                    int kk = k0 - 512;
                    if (c >= 1000) {
                        const float* p = &redh[((size_t)(c - 1000) * NB + b) * DN + kk];
                        v.x = cohLd(p); v.y = cohLd(p + 1); v.z = cohLd(p + 2); v.w = cohLd(p + 3);
                    } else if (c >= 0) v = *(const float4*)&bufh[((size_t)b * LN + c) * DN + kk];
                } else {
                    const float* p = &th[((size_t)par * NB + b) * TKN + (k0 - 768)];
                    v.x = cohLd(p); v.y = cohLd(p + 1); v.z = cohLd(p + 2); v.w = cohLd(p + 3);
                }
                *(float4*)&xs[row][k0] = v;
            } else {
                int g2 = g - 448;
                int row = g2 & 3, k0 = (g2 >> 2) * 4;
                int b = bg2 * 4 + row;
                float4 v = {0.f, 0.f, 0.f, 0.f};
                if (k0 < 256) {
                    int c = s2code[t * NB + b];
                    if (c >= 1000) {
                        const float* p = &redh[((size_t)(c - 1000) * NB + b) * DN + k0];
                        v.x = cohLd(p); v.y = cohLd(p + 1); v.z = cohLd(p + 2); v.w = cohLd(p + 3);
                    } else if (c >= 0) v = *(const float4*)&bufh[((size_t)b * LN + c) * DN + k0];
                } else {
                    int c = s1code[t * NB + b];
                    int kk = k0 - 256;
                    if (c >= 1000) {
                        const float* p = &redh[((size_t)(c - 1000) * NB + b) * DN + kk];
                        v.x = cohLd(p); v.y = cohLd(p + 1); v.z = cohLd(p + 2); v.w = cohLd(p + 3);
                    } else if (c >= 0) v = *(const float4*)&bufh[((size_t)b * LN + c) * DN + kk];
                }
                *(float4*)&xs2[row][k0] = v;
            }
        }
        __syncthreads();

        // ============ concurrent GEMMs: waves 0-3 P1, waves 4-7 P2s ============
        float acc[5][4];   // P2 accumulators live across barrier A in registers
        if (w < 4) {
            int c4 = lane & 15, kq = lane >> 4;
            int kbase = w * 224 + kq;
            const float4* wp = (const float4*)(WAx + ((size_t)jg * 896 + kbase) * 64) + c4;
            float4 a0 = {0.f, 0.f, 0.f, 0.f}, a1 = {0.f, 0.f, 0.f, 0.f};
            #pragma unroll 4
            for (int i = 0; i < 56; ++i) {
                float4 wv = wp[(size_t)i * 64];        // wave: 1KB contiguous / instr
                float x0 = xs[0][kbase + i * 4];
                float x1 = xs[1][kbase + i * 4];
                a0.x += x0 * wv.x; a0.y += x0 * wv.y; a0.z += x0 * wv.z; a0.w += x0 * wv.w;
                a1.x += x1 * wv.x; a1.y += x1 * wv.y; a1.z += x1 * wv.z; a1.w += x1 * wv.w;
            }
            part4[w * 4 + kq][c4][0] = a0;
            part4[w * 4 + kq][c4][1] = a1;
        } else if (red) {
            int t2 = tid - 256, jj = t2 & 15, ks = t2 >> 4;   // 16 j x 16 kslices
            #pragma unroll
            for (int g = 0; g < 5; ++g)
                #pragma unroll
                for (int b4 = 0; b4 < 4; ++b4) acc[g][b4] = 0.f;
            const float* rb = WBx + ((size_t)jgw * 640 + ks * 32) * 128 + jj * 8;
            #pragma unroll 4
            for (int i = 0; i < 32; ++i) {
                const float* rr = rb + (size_t)i * 128;
                float4 w0 = *(const float4*)rr;
                float w4v = rr[4];
                int k = ks * 32 + i;
                float x0 = xs2[0][k], x1 = xs2[1][k], x2 = xs2[2][k], x3 = xs2[3][k];
                acc[0][0] += x0 * w0.x; acc[1][0] += x0 * w0.y; acc[2][0] += x0 * w0.z; acc[3][0] += x0 * w0.w; acc[4][0] += x0 * w4v;
                acc[0][1] += x1 * w0.x; acc[1][1] += x1 * w0.y; acc[2][1] += x1 * w0.z; acc[3][1] += x1 * w0.w; acc[4][1] += x1 * w4v;
                acc[0][2] += x2 * w0.x; acc[1][2] += x2 * w0.y; acc[2][2] += x2 * w0.z; acc[3][2] += x2 * w0.w; acc[4][2] += x2 * w4v;
                acc[0][3] += x3 * w0.x; acc[1][3] += x3 * w0.y; acc[2][3] += x3 * w0.z; acc[3][3] += x3 * w0.w; acc[4][3] += x3 * w4v;
            }
        }
        __syncthreads();

        // ============ P1 reduce + tracker LSTM ============
        if (tid < 128) {
            int bl_ = tid >> 6, cl = tid & 63;
            int c4 = cl >> 2, ci = cl & 3;
            float s = 0.f;
            #pragma unroll
            for (int ss = 0; ss < 16; ++ss) {
                const float4& p4 = part4[ss][c4][bl_];
                s += (ci == 0) ? p4.x : (ci == 1) ? p4.y : (ci == 2) ? p4.z : p4.w;
            }
            if (t > 0) s += blA[jg * 64 + cl];
            gsum[bl_][cl] = s;
        }
        __syncthreads();
        if (tid < 32) {
            int bl_ = tid >> 4, jj = tid & 15;
            int b = bg1 * 2 + bl_;
            int j = jg * 16 + jj;
            float4 g4 = *(const float4*)&gsum[bl_][jj * 4];     // a,i,f,o
            float tco = tc[((size_t)par * NB + b) * TKN + j];
            float c2v = tanhf(g4.x) * sigf(g4.y) + sigf(g4.z) * tco;
            float h2 = sigf(g4.w) * tanhf(c2v);
            tc[((size_t)(par ^ 1) * NB + b) * TKN + j] = c2v;
            cohSt(&th[((size_t)(par ^ 1) * NB + b) * TKN + j], h2);
        }
        gbar(slots, flag, ph);   // barrier A: th2 visible

        if (red) {
            // ============ WT part (K=128) + reduce + TreeLSTM ============
            {
                int b4 = tid >> 7, kk = tid & 127;
                xst[b4][kk] = cohLd(&th[((size_t)(par ^ 1) * NB + bg2 * 4 + b4) * TKN + kk]);
            }
            __syncthreads();
            if (w >= 4) {
                int t2 = tid - 256, jj = t2 & 15, ks = t2 >> 4;
                const float* rb = WBx + ((size_t)jgw * 640 + 512 + ks * 8) * 128 + jj * 8;
                #pragma unroll
                for (int i = 0; i < 8; ++i) {
                    const float* rr = rb + (size_t)i * 128;
                    float4 w0 = *(const float4*)rr;
                    float w4v = rr[4];
                    int kk2 = ks * 8 + i;
                    float x0 = xst[0][kk2], x1 = xst[1][kk2], x2 = xst[2][kk2], x3 = xst[3][kk2];
                    acc[0][0] += x0 * w0.x; acc[1][0] += x0 * w0.y; acc[2][0] += x0 * w0.z; acc[3][0] += x0 * w0.w; acc[4][0] += x0 * w4v;
                    acc[0][1] += x1 * w0.x; acc[1][1] += x1 * w0.y; acc[2][1] += x1 * w0.z; acc[3][1] += x1 * w0.w; acc[4][1] += x1 * w4v;
                    acc[0][2] += x2 * w0.x; acc[1][2] += x2 * w0.y; acc[2][2] += x2 * w0.z; acc[3][2] += x2 * w0.w; acc[4][2] += x2 * w4v;
                    acc[0][3] += x3 * w0.x; acc[1][3] += x3 * w0.y; acc[2][3] += x3 * w0.z; acc[3][3] += x3 * w0.w; acc[4][3] += x3 * w4v;
                }
                #pragma unroll
                for (int g = 0; g < 5; ++g)
                    #pragma unroll
                    for (int b4 = 0; b4 < 4; ++b4)
                        part2[ks][jj][g * 4 + b4] = acc[g][b4];
            }
            __syncthreads();
            if (tid < 320) {
                int g = tid >> 6, r = tid & 63;
                int bl_ = r >> 4, jj = r & 15;
                float s = 0.f;
                #pragma unroll
                for (int ks = 0; ks < 16; ++ks) s += part2[ks][jj][g * 4 + bl_];
                gsum2[bl_][g][jj] = s;
            }
            __syncthreads();
            if (tid < 64) {
                int bl_ = tid >> 4, jj = tid & 15;
                int b = bg2 * 4 + bl_;
                int wk = wkA[t * NB + b];
                if (wk >= 0) {
                    int j = jgw * 16 + jj;
                    float ga  = gsum2[bl_][0][jj] + bLv[0 * 256 + j];
                    float gi  = gsum2[bl_][1][jj] + bLv[1 * 256 + j];
                    float gf1 = gsum2[bl_][2][jj] + bLv[2 * 256 + j];
                    float gf2 = gsum2[bl_][3][jj] + bLv[3 * 256 + j];
                    float go  = gsum2[bl_][4][jj] + bLv[4 * 256 + j];
                    int c1 = s1code[t * NB + b], c2 = s2code[t * NB + b];
                    float s2cv = (c2 == -1) ? 0.f
                                : ((c2 >= 1000) ? redc[((size_t)(c2 - 1000) * NB + b) * DN + j]
                                                : bufc[((size_t)b * LN + c2) * DN + j]);
                    float s1cv = (c1 == -1) ? 0.f
                                : ((c1 >= 1000) ? redc[((size_t)(c1 - 1000) * NB + b) * DN + j]
                                                : bufc[((size_t)b * LN + c1) * DN + j]);
                    float cc = tanhf(ga) * sigf(gi) + sigf(gf1) * s2cv + sigf(gf2) * s1cv;
                    float hh = sigf(go) * tanhf(cc);
                    cohSt(&redh[((size_t)wk * NB + b) * DN + j], hh);   // cross-WG
                    redc[((size_t)wk * NB + b) * DN + j] = cc;          // owner-stable
                }
            }
            gbar(slots, flag, ph);   // barrier C: redh visible
        }
    }

    // ===== final output: P2-owner (b,j) writes its slice =====
    if (tid < 64) {
        int bl_ = tid >> 4, jj = tid & 15;
        int b = bg2 * 4 + bl_;
        int j = jgw * 16 + jj;
        int c = fcode[b];
        float h = 0.f, cv = 0.f;
        if (c >= 1000) {
            h  = cohLd(&redh[((size_t)(c - 1000) * NB + b) * DN + j]);
            cv = redc[((size_t)(c - 1000) * NB + b) * DN + j];
        } else if (c >= 0) {
            h  = bufh[((size_t)b * LN + c) * DN + j];
            cv = bufc[((size_t)b * LN + c) * DN + j];
        }
        out[(size_t)b * 2 * DN + j]      = h;
        out[(size_t)b * 2 * DN + DN + j] = cv;
    }
}

extern "C" void kernel_launch(void* const* d_in, const int* in_sizes, int n_in,
                              void* d_out, int out_size, void* d_ws, size_t ws_size,
                              hipStream_t stream) {
    const float* bufh = (const float*)d_in[0];
    const float* bufc = (const float*)d_in[1];
    const float* Wb   = (const float*)d_in[2];
    const float* W1   = (const float*)d_in[3];
    const float* W2   = (const float*)d_in[4];
    const float* Wl   = (const float*)d_in[5];
    const float* blv  = (const float*)d_in[6];
    const float* WLm  = (const float*)d_in[7];
    const float* bLv  = (const float*)d_in[8];
    const float* WR   = (const float*)d_in[9];
    const float* WT   = (const float*)d_in[10];
    const int* trans  = (const int*)d_in[11];
    float* out = (float*)d_out;

    char* p = (char*)d_ws;
    auto carve = [&](size_t bytes) -> char* {
        char* r = p;
        p += (bytes + 255) & ~(size_t)255;
        return r;
    };
    int* tbcode = (int*)carve((size_t)TN * NB * 4);
    int* s1code = (int*)carve((size_t)TN * NB * 4);
    int* s2code = (int*)carve((size_t)TN * NB * 4);
    int* wkA    = (int*)carve((size_t)TN * NB * 4);
    int* fcode  = (int*)carve((size_t)NB * 4);
    int* anyred = (int*)carve((size_t)TN * 4);
    float* th   = (float*)carve((size_t)2 * NB * TKN * 4);
    float* tc   = (float*)carve((size_t)2 * NB * TKN * 4);
    float* redh = (float*)carve((size_t)RMAX * NB * DN * 4);
    float* redc = (float*)carve((size_t)RMAX * NB * DN * 4);
    float* WAx  = (float*)carve((size_t)8 * 896 * 64 * 4);
    float* blA  = (float*)carve((size_t)512 * 4);
    float* WBx  = (float*)carve((size_t)16 * 640 * 128 * 4);
    unsigned* slots = (unsigned*)carve((size_t)NWG * 16 * 4);
    unsigned* flag  = (unsigned*)carve(256);

    hipMemsetAsync(th, 0, (size_t)2 * NB * TKN * 4, stream);
    hipMemsetAsync(tc, 0, (size_t)2 * NB * TKN * 4, stream);
    hipMemsetAsync(slots, 0, (size_t)NWG * 16 * 4, stream);
    hipMemsetAsync(flag, 0, 256, stream);

    k_sched<<<1, 64, 0, stream>>>(trans, tbcode, s1code, s2code, wkA, fcode, anyred);
    k_pack_a<<<(8 * 896 * 64 + 255) / 256, 256, 0, stream>>>(Wb, W1, W2, Wl, blv, WAx, blA);
    k_pack_b<<<(16 * 640 * 128 + 255) / 256, 256, 0, stream>>>(WLm, WR, WT, WBx);
    k_spinn<<<NWG, NT, 0, stream>>>(bufh, bufc, WAx, blA, WBx, bLv,
                                    tbcode, s1code, s2code, wkA, fcode, anyred,
                                    th, tc, redh, redc, slots, flag, out);
}